// Round 1
// baseline (350.482 us; speedup 1.0000x reference)
//
#include <hip/hip_runtime.h>
#include <hip/hip_bf16.h>
#include <stdint.h>

#define MODS 7
#define NMOD 1024
#define EMOD 32768
#define NN (MODS*NMOD)   // 7168 nodes
#define EE (MODS*EMOD)   // 229376 edges
#define FF 128
#define DD 64
#define HHD 4
#define HCC 256
#define KC 4             // key chunks for flash attention

static __device__ __forceinline__ float lrelu(float x){ return x > 0.f ? x : 0.2f*x; }

// ---------------- CSR build ----------------
__global__ void k_count(const int* __restrict__ dst, int* __restrict__ cnt) {
  int e = blockIdx.x*256 + threadIdx.x;
  if (e < EE) atomicAdd(&cnt[dst[e]], 1);
}

__global__ void k_scan(const int* __restrict__ cnt, int* __restrict__ rs) {
  __shared__ int sd[1024];
  __shared__ int carry_s;
  if (threadIdx.x == 0) carry_s = 0;
  __syncthreads();
  for (int base = 0; base < NN; base += 1024) {
    int i = base + threadIdx.x;
    int v = (i < NN) ? cnt[i] : 0;
    sd[threadIdx.x] = v;
    __syncthreads();
    for (int off = 1; off < 1024; off <<= 1) {
      int t = (threadIdx.x >= off) ? sd[threadIdx.x - off] : 0;
      __syncthreads();
      sd[threadIdx.x] += t;
      __syncthreads();
    }
    if (i < NN) rs[i] = carry_s + sd[threadIdx.x] - v;   // exclusive
    int tot = sd[1023];
    __syncthreads();
    if (threadIdx.x == 0) carry_s += tot;
    __syncthreads();
  }
  if (threadIdx.x == 0) rs[NN] = carry_s;
}

__global__ void k_fill(const int* __restrict__ src, const int* __restrict__ dst,
                       const int* __restrict__ rs, int* __restrict__ fill,
                       int* __restrict__ csr_src) {
  int e = blockIdx.x*256 + threadIdx.x;
  if (e < EE) {
    int d = dst[e];
    int pos = rs[d] + atomicAdd(&fill[d], 1);
    csr_src[pos] = src[e];
  }
}

// ---------------- generic per-module SGEMM: C[n, :] = A[n, :] @ B[m] (+bias) ----------------
// A: [NN, K] node-major. B: per module, [K, JT] (TB=false) or [JT, K] (TB=true).
// bias (if non-null): [MODS, JT]. grid = MODS * 16 * (JT/64), block = 256.
template<int K, int JT, bool TB>
__global__ __launch_bounds__(256) void k_gemm(const float* __restrict__ A,
    const float* __restrict__ B, const float* __restrict__ bias, float* __restrict__ C) {
  constexpr int jt = JT/64;
  int b = blockIdx.x;
  int m = b / (16*jt);
  int r = b - m*16*jt;
  int rt = r / jt, ct = r - rt*jt;
  int row0 = m*NMOD + rt*64;
  int col0 = ct*64;
  __shared__ float As[64][33];
  __shared__ float Bs[32][65];
  float acc[4][4] = {};
  int tid = threadIdx.x;
  int tr = (tid >> 4) << 2;
  int tc = (tid & 15) << 2;
  const float* Bm = B + (size_t)m*K*JT;
  for (int k0 = 0; k0 < K; k0 += 32) {
    #pragma unroll
    for (int i = 0; i < 8; ++i) {
      int idx = tid + i*256;
      int rr = idx >> 5, kk = idx & 31;
      As[rr][kk] = A[(size_t)(row0+rr)*K + k0 + kk];
    }
    #pragma unroll
    for (int i = 0; i < 8; ++i) {
      int idx = tid + i*256;
      if (!TB) {
        int kk = idx >> 6, jj = idx & 63;
        Bs[kk][jj] = Bm[(size_t)(k0+kk)*JT + col0 + jj];
      } else {
        int jj = idx >> 5, kk = idx & 31;
        Bs[kk][jj] = Bm[(size_t)(col0+jj)*K + k0 + kk];
      }
    }
    __syncthreads();
    #pragma unroll
    for (int kk = 0; kk < 32; ++kk) {
      float a0 = As[tr+0][kk], a1 = As[tr+1][kk], a2 = As[tr+2][kk], a3 = As[tr+3][kk];
      float b0 = Bs[kk][tc+0], b1 = Bs[kk][tc+1], b2 = Bs[kk][tc+2], b3 = Bs[kk][tc+3];
      acc[0][0] += a0*b0; acc[0][1] += a0*b1; acc[0][2] += a0*b2; acc[0][3] += a0*b3;
      acc[1][0] += a1*b0; acc[1][1] += a1*b1; acc[1][2] += a1*b2; acc[1][3] += a1*b3;
      acc[2][0] += a2*b0; acc[2][1] += a2*b1; acc[2][2] += a2*b2; acc[2][3] += a2*b3;
      acc[3][0] += a3*b0; acc[3][1] += a3*b1; acc[3][2] += a3*b2; acc[3][3] += a3*b3;
    }
    __syncthreads();
  }
  #pragma unroll
  for (int i = 0; i < 4; ++i) {
    #pragma unroll
    for (int j = 0; j < 4; ++j) {
      float v = acc[i][j];
      if (bias) v += bias[m*JT + col0 + tc + j];
      C[(size_t)(row0+tr+i)*JT + col0 + tc + j] = v;
    }
  }
}

// ---------------- GAT attention scores: es/ed per (node, head) ----------------
template<int H>
__global__ void k_scores(const float* __restrict__ h, const float* __restrict__ a_s,
                         const float* __restrict__ a_d, float* __restrict__ es,
                         float* __restrict__ ed) {
  int gw = (blockIdx.x * blockDim.x + threadIdx.x) >> 6;
  int lane = threadIdx.x & 63;
  if (gw >= NN*H) return;
  int n = gw / H, hh = gw - n*H;
  int m = n >> 10;
  float v = h[(size_t)(n*H + hh)*64 + lane];
  float s = v * a_s[(m*H + hh)*64 + lane];
  float d = v * a_d[(m*H + hh)*64 + lane];
  #pragma unroll
  for (int off = 32; off >= 1; off >>= 1) { s += __shfl_down(s, off); d += __shfl_down(d, off); }
  if (lane == 0) { es[n*H + hh] = s; ed[n*H + hh] = d; }
}

// ---------------- GAT gather-aggregation (one wave per (node, head)) ----------------
// Softmax without max-subtraction: scores are O(1), exp never overflows; identical math.
template<int H>
__global__ void k_agg(const float* __restrict__ h, const float* __restrict__ es,
                      const float* __restrict__ ed, const int* __restrict__ rs,
                      const int* __restrict__ csr_src, const float* __restrict__ bias,
                      float* __restrict__ out) {
  int gw = blockIdx.x*4 + (threadIdx.x >> 6);
  int lane = threadIdx.x & 63;
  if (gw >= NN*H) return;
  int n = gw / H, hh = gw - n*H;
  int m = n >> 10;
  float edv = ed[n*H + hh];
  // self-loop
  float p0 = __expf(lrelu(es[n*H + hh] + edv));
  float den = p0;
  float acc = p0 * h[(size_t)(n*H + hh)*64 + lane];
  int beg = rs[n], end = rs[n+1];
  for (int i = beg; i < end; ++i) {
    int s = csr_src[i];
    float p = __expf(lrelu(es[s*H + hh] + edv));
    den += p;
    acc += p * h[(size_t)(s*H + hh)*64 + lane];
  }
  float v = acc/den + bias[(m*H + hh)*64 + lane];
  out[(size_t)(n*H + hh)*64 + lane] = fmaxf(v, 0.f);
}

// ---------------- per-module self-attention (flash, dh=16, no-max softmax) ----------------
// block = 256 (4 waves = 4 heads), lane = query; grid = MODS*16*KC; keys split into KC chunks.
__global__ __launch_bounds__(256) void k_attn(const float* __restrict__ qkv,
    float* __restrict__ pd, float* __restrict__ pacc) {
  int b = blockIdx.x;
  int kc = b & (KC-1); b >>= 2;
  int qt = b & 15; int m = b >> 4;
  int h = threadIdx.x >> 6;
  int lane = threadIdx.x & 63;
  int n = m*NMOD + qt*64 + lane;
  float q[16];
  const float* qrow = qkv + (size_t)n*192 + h*16;
  #pragma unroll
  for (int c = 0; c < 16; ++c) q[c] = qrow[c]*0.25f;   // 1/sqrt(16)
  float den = 0.f, acc[16] = {};
  __shared__ float Ks[4][64][17];
  __shared__ float Vs[4][64][17];
  int lk = threadIdx.x >> 2, lh = threadIdx.x & 3;
  for (int tile = 0; tile < 4; ++tile) {
    int key0 = kc*256 + tile*64;
    __syncthreads();
    const float* srck = qkv + (size_t)(m*NMOD + key0 + lk)*192 + 64 + lh*16;
    #pragma unroll
    for (int c = 0; c < 16; ++c) Ks[lh][lk][c] = srck[c];
    #pragma unroll
    for (int c = 0; c < 16; ++c) Vs[lh][lk][c] = srck[64 + c];
    __syncthreads();
    #pragma unroll 4
    for (int j = 0; j < 64; ++j) {
      float s = 0.f;
      #pragma unroll
      for (int c = 0; c < 16; ++c) s += q[c]*Ks[h][j][c];
      float p = __expf(s);
      den += p;
      #pragma unroll
      for (int c = 0; c < 16; ++c) acc[c] += p*Vs[h][j][c];
    }
  }
  size_t o = ((size_t)(n*4 + h)*KC + kc);
  pd[o] = den;
  #pragma unroll
  for (int c = 0; c < 16; ++c) pacc[o*16 + c] = acc[c];
}

__global__ void k_attn_combine(const float* __restrict__ pd, const float* __restrict__ pacc,
                               float* __restrict__ attn) {
  int t = blockIdx.x*256 + threadIdx.x;   // (n, h)
  if (t >= NN*4) return;
  float den = 0.f;
  #pragma unroll
  for (int kc = 0; kc < KC; ++kc) den += pd[(size_t)t*KC + kc];
  float inv = 1.f/den;
  #pragma unroll
  for (int c = 0; c < 16; ++c) {
    float s = 0.f;
    #pragma unroll
    for (int kc = 0; kc < KC; ++kc) s += pacc[((size_t)t*KC + kc)*16 + c];
    attn[(size_t)(t >> 2)*64 + (t & 3)*16 + c] = s*inv;
  }
}

// ---------------- node-mean + folded output projection -> reps ----------------
// reps[m] = mean_n(attn[n]) @ out_w[m]^T + out_b[m]  (projection commutes with mean)
__global__ void k_reps(const float* __restrict__ attn, const float* __restrict__ out_w,
                       const float* __restrict__ out_b, float* __restrict__ reps,
                       float* __restrict__ dout) {
  int m = blockIdx.x;
  __shared__ float part[4][64];
  __shared__ float abar[64];
  int c = threadIdx.x & 63, pp = threadIdx.x >> 6;
  float s = 0.f;
  const float* base = attn + (size_t)m*NMOD*64;
  for (int i = pp*256; i < pp*256 + 256; ++i) s += base[(size_t)i*64 + c];
  part[pp][c] = s;
  __syncthreads();
  if (pp == 0) abar[c] = (part[0][c]+part[1][c]+part[2][c]+part[3][c]) * (1.f/NMOD);
  __syncthreads();
  if (threadIdx.x < 64) {
    int j = threadIdx.x;
    float r = out_b[m*64 + j];
    const float* wr = out_w + (size_t)m*64*64 + (size_t)j*64;
    #pragma unroll
    for (int k = 0; k < 64; ++k) r += abar[k]*wr[k];
    reps[m*64 + j] = r;
    dout[2 + m*64 + j] = r;     // Output 1
  }
}

// ---------------- cross-attention + fusion + classifier (single block) ----------------
__global__ __launch_bounds__(256) void k_final(const float* __restrict__ reps,
    const float* __restrict__ ca_in_w, const float* __restrict__ ca_in_b,
    const float* __restrict__ ca_out_w, const float* __restrict__ ca_out_b,
    const float* __restrict__ fusion_w, const float* __restrict__ fc_w,
    const float* __restrict__ fc_b, const float* __restrict__ c1_w,
    const float* __restrict__ c1_b, const float* __restrict__ c2_w,
    const float* __restrict__ c2_b, float* __restrict__ dout) {
  __shared__ float R[7][64];
  __shared__ float QKV[7][192];
  __shared__ float alpha[4][7][7];
  __shared__ float O[7][64];
  __shared__ float CR[7][64];
  __shared__ float W[7];
  __shared__ float FU[64];
  __shared__ float HM[32];
  int tid = threadIdx.x;
  for (int i = tid; i < 7*64; i += 256) R[i/64][i%64] = reps[i];
  __syncthreads();
  for (int i = tid; i < 7*192; i += 256) {
    int r = i/192, j = i - r*192;
    float s = ca_in_b[j];
    for (int k = 0; k < 64; ++k) s += R[r][k]*ca_in_w[j*64 + k];
    QKV[r][j] = s;
  }
  __syncthreads();
  if (tid < 28) {
    int hh = tid/7, qi = tid - hh*7;
    float p[7]; float den = 0.f;
    for (int ki = 0; ki < 7; ++ki) {
      float s = 0.f;
      for (int c = 0; c < 16; ++c) s += QKV[qi][hh*16+c]*QKV[ki][64 + hh*16 + c];
      p[ki] = __expf(s*0.25f);
      den += p[ki];
    }
    for (int ki = 0; ki < 7; ++ki) alpha[hh][qi][ki] = p[ki]/den;
  }
  __syncthreads();
  for (int i = tid; i < 7*64; i += 256) {
    int qi = i/64, j = i - qi*64;
    int hh = j >> 4;
    float s = 0.f;
    for (int ki = 0; ki < 7; ++ki) s += alpha[hh][qi][ki]*QKV[ki][128 + j];
    O[qi][j] = s;
  }
  __syncthreads();
  for (int i = tid; i < 7*64; i += 256) {
    int qi = i/64, j = i - qi*64;
    float s = ca_out_b[j];
    for (int k = 0; k < 64; ++k) s += O[qi][k]*ca_out_w[j*64 + k];
    CR[qi][j] = s;
  }
  if (tid == 0) {
    float p[7]; float den = 0.f;
    for (int i = 0; i < 7; ++i) { p[i] = __expf(fusion_w[i]); den += p[i]; }
    for (int i = 0; i < 7; ++i) W[i] = p[i]/den;
  }
  __syncthreads();
  if (tid < 64) {
    float s = fc_b[tid];
    for (int i = 0; i < 448; ++i) s += CR[i>>6][i&63]*W[i>>6]*fc_w[(size_t)i*64 + tid];
    FU[tid] = s;
  }
  __syncthreads();
  if (tid < 32) {
    float s = c1_b[tid];
    for (int k = 0; k < 64; ++k) s += FU[k]*c1_w[k*32 + tid];
    HM[tid] = fmaxf(s, 0.f);
  }
  __syncthreads();
  if (tid < 2) {
    float s = c2_b[tid];
    for (int k = 0; k < 32; ++k) s += HM[k]*c2_w[k*2 + tid];
    dout[tid] = s;              // Output 0
  }
}

extern "C" void kernel_launch(void* const* d_in, const int* in_sizes, int n_in,
                              void* d_out, int out_size, void* d_ws, size_t ws_size,
                              hipStream_t stream) {
  (void)in_sizes; (void)n_in; (void)out_size; (void)ws_size;
  const float* x       = (const float*)d_in[0];
  const int*   ei      = (const int*)d_in[1];
  const float* g1_w    = (const float*)d_in[3];
  const float* g1_as   = (const float*)d_in[4];
  const float* g1_ad   = (const float*)d_in[5];
  const float* g1_b    = (const float*)d_in[6];
  const float* g2_w    = (const float*)d_in[7];
  const float* g2_as   = (const float*)d_in[8];
  const float* g2_ad   = (const float*)d_in[9];
  const float* g2_b    = (const float*)d_in[10];
  const float* sa_in_w = (const float*)d_in[11];
  const float* sa_in_b = (const float*)d_in[12];
  const float* sa_out_w= (const float*)d_in[13];
  const float* sa_out_b= (const float*)d_in[14];
  const float* ca_in_w = (const float*)d_in[15];
  const float* ca_in_b = (const float*)d_in[16];
  const float* ca_out_w= (const float*)d_in[17];
  const float* ca_out_b= (const float*)d_in[18];
  const float* fusion_w= (const float*)d_in[19];
  const float* fc_w    = (const float*)d_in[20];
  const float* fc_b    = (const float*)d_in[21];
  const float* c1_w    = (const float*)d_in[22];
  const float* c1_b    = (const float*)d_in[23];
  const float* c2_w    = (const float*)d_in[24];
  const float* c2_b    = (const float*)d_in[25];
  float* dout = (float*)d_out;

  const int* src = ei;        // edge_index[0]
  const int* dst = ei + EE;   // edge_index[1]

  // ---- workspace carve (with aliasing of dead buffers) ----
  char* p = (char*)d_ws;
  int* cnt     = (int*)p; p += (size_t)NN*sizeof(int);
  int* fill    = (int*)p; p += (size_t)NN*sizeof(int);
  int* rs      = (int*)p; p += (size_t)(NN+1)*sizeof(int);
  int* csr_src = (int*)p; p += (size_t)EE*sizeof(int);
  p = (char*)(((uintptr_t)p + 255) & ~(uintptr_t)255);
  float* h1   = (float*)p; p += (size_t)NN*256*4;   // aliased later by qkv
  float* es1  = (float*)p; p += (size_t)NN*4*4;
  float* ed1  = (float*)p; p += (size_t)NN*4*4;
  float* gat1 = (float*)p; p += (size_t)NN*256*4;   // aliased later by pacc
  float* h2   = (float*)p; p += (size_t)NN*64*4;    // aliased later by pd
  float* es2  = (float*)p; p += (size_t)NN*4;
  float* ed2  = (float*)p; p += (size_t)NN*4;
  float* z    = (float*)p; p += (size_t)NN*64*4;
  float* attn = (float*)p; p += (size_t)NN*64*4;
  float* reps = (float*)p; p += (size_t)MODS*64*4;
  float* qkv  = h1;    // h1 dead after k_agg<4>
  float* pacc = gat1;  // gat1 dead after k_gemm<256,64>
  float* pd   = h2;    // h2 dead after k_agg<1>

  hipMemsetAsync(cnt, 0, 2*(size_t)NN*sizeof(int), stream);   // cnt + fill
  k_count<<<(EE+255)/256, 256, 0, stream>>>(dst, cnt);
  k_scan<<<1, 1024, 0, stream>>>(cnt, rs);
  k_fill<<<(EE+255)/256, 256, 0, stream>>>(src, dst, rs, fill, csr_src);

  // GAT layer 1: h1 = x @ g1_w[m]; scores; aggregate -> gat1 (relu(agg + b))
  k_gemm<128,256,false><<<MODS*16*4, 256, 0, stream>>>(x, g1_w, nullptr, h1);
  k_scores<4><<<(NN*4*64)/256, 256, 0, stream>>>(h1, g1_as, g1_ad, es1, ed1);
  k_agg<4><<<NN, 256, 0, stream>>>(h1, es1, ed1, rs, csr_src, g1_b, gat1);

  // GAT layer 2
  k_gemm<256,64,false><<<MODS*16, 256, 0, stream>>>(gat1, g2_w, nullptr, h2);
  k_scores<1><<<(NN*64)/256, 256, 0, stream>>>(h2, g2_as, g2_ad, es2, ed2);
  k_agg<1><<<NN/4, 256, 0, stream>>>(h2, es2, ed2, rs, csr_src, g2_b, z);

  // self-attention: qkv proj (z @ in_w^T + b), flash attention, combine
  k_gemm<64,192,true><<<MODS*16*3, 256, 0, stream>>>(z, sa_in_w, sa_in_b, qkv);
  k_attn<<<MODS*16*KC, 256, 0, stream>>>(qkv, pd, pacc);
  k_attn_combine<<<(NN*4+255)/256, 256, 0, stream>>>(pd, pacc, attn);

  // node-mean + folded out-proj -> reps (writes Output 1)
  k_reps<<<MODS, 256, 0, stream>>>(attn, sa_out_w, sa_out_b, reps, dout);

  // cross-attention + fusion + classifier (writes Output 0)
  k_final<<<1, 256, 0, stream>>>(reps, ca_in_w, ca_in_b, ca_out_w, ca_out_b,
                                 fusion_w, fc_w, fc_b, c1_w, c1_b, c2_w, c2_b, dout);
}

// Round 2
// 257.466 us; speedup vs baseline: 1.3613x; 1.3613x over previous
//
#include <hip/hip_runtime.h>
#include <hip/hip_bf16.h>
#include <stdint.h>

#define MODS 7
#define NMOD 1024
#define EMOD 32768
#define NN (MODS*NMOD)   // 7168 nodes
#define EE (MODS*EMOD)   // 229376 edges
#define KC2 2            // block-level key chunks (x4 waves = 8-way key split)

static __device__ __forceinline__ float lrelu(float x){ return x > 0.f ? x : 0.2f*x; }

// ---------------- CSR build ----------------
__global__ void k_count(const int* __restrict__ dst, int* __restrict__ cnt) {
  int e = blockIdx.x*256 + threadIdx.x;
  if (e < EE) atomicAdd(&cnt[dst[e]], 1);
}

__global__ void k_scan(const int* __restrict__ cnt, int* __restrict__ rs) {
  // 1 block, 1024 threads; wave-shuffle scan
  __shared__ int wsum[16];
  __shared__ int carry;
  int tid = threadIdx.x, lane = tid & 63, wid = tid >> 6;
  if (tid == 0) carry = 0;
  __syncthreads();
  for (int base = 0; base < NN; base += 1024) {
    int i = base + tid;
    int v = (i < NN) ? cnt[i] : 0;
    int x = v;
    #pragma unroll
    for (int off = 1; off < 64; off <<= 1) { int t = __shfl_up(x, off); if (lane >= off) x += t; }
    if (lane == 63) wsum[wid] = x;
    __syncthreads();
    if (wid == 0 && lane < 16) {
      int y = wsum[lane];
      #pragma unroll
      for (int off = 1; off < 16; off <<= 1) { int t = __shfl_up(y, off, 16); if (lane >= off) y += t; }
      wsum[lane] = y;
    }
    __syncthreads();
    int woff = wid ? wsum[wid-1] : 0;
    int c = carry;
    if (i < NN) rs[i] = x - v + woff + c;   // exclusive
    __syncthreads();
    if (tid == 0) carry += wsum[15];
    __syncthreads();
  }
  if (threadIdx.x == 0) rs[NN] = carry;
}

__global__ void k_fill(const int* __restrict__ src, const int* __restrict__ dst,
                       const int* __restrict__ rs, int* __restrict__ fill,
                       int* __restrict__ csr_src, int* __restrict__ epos) {
  int e = blockIdx.x*256 + threadIdx.x;
  if (e < EE) {
    int d = dst[e];
    int pos = rs[d] + atomicAdd(&fill[d], 1);
    csr_src[pos] = src[e];
    epos[e] = pos;
  }
}

// ---------------- per-module SGEMM, vectorized LDS ----------------
// A: [NN,K]; B per module [K,JT] (TB=false) or [JT,K] (TB=true); C partials at ks*NN*JT.
// grid = MODS * (NMOD/RT) * (JT/64) * KS, block 256.
template<int K, int JT, bool TB, int RT, int KS>
__global__ __launch_bounds__(256) void k_gemm(const float* __restrict__ A,
    const float* __restrict__ B, const float* __restrict__ bias, float* __restrict__ C) {
  constexpr int jt = JT/64;
  constexpr int rtiles = NMOD/RT;
  constexpr int RPT = RT/16;
  constexpr int KCHUNK = K/KS;
  int b = blockIdx.x;
  int ks = b % KS; b /= KS;
  int ct = b % jt; b /= jt;
  int rt = b % rtiles; b /= rtiles;
  int m = b;
  int row0 = m*NMOD + rt*RT;
  int col0 = ct*64;
  __shared__ float Ast[32][RT+4];  // transposed: [kk][row]
  __shared__ float Bs[32][68];
  float acc[RPT][4] = {};
  int tid = threadIdx.x;
  int tr = (tid >> 4) * RPT;
  int tc = (tid & 15) * 4;
  const float* Bm = B + (size_t)m*K*JT;
  for (int k0 = ks*KCHUNK; k0 < (ks+1)*KCHUNK; k0 += 32) {
    constexpr int ANUM = RT*32/1024;
    #pragma unroll
    for (int i = 0; i < ANUM; ++i) {
      int it = tid + i*256;
      int rr = it >> 3, kk0 = (it & 7)*4;
      float4 t = *(const float4*)&A[(size_t)(row0+rr)*K + k0 + kk0];
      Ast[kk0+0][rr] = t.x; Ast[kk0+1][rr] = t.y; Ast[kk0+2][rr] = t.z; Ast[kk0+3][rr] = t.w;
    }
    #pragma unroll
    for (int i = 0; i < 2; ++i) {
      int it = tid + i*256;
      if (!TB) {
        int kk = it >> 4, jj0 = (it & 15)*4;
        float4 t = *(const float4*)&Bm[(size_t)(k0+kk)*JT + col0 + jj0];
        Bs[kk][jj0] = t.x; Bs[kk][jj0+1] = t.y; Bs[kk][jj0+2] = t.z; Bs[kk][jj0+3] = t.w;
      } else {
        int jj = it >> 3, kk0 = (it & 7)*4;
        float4 t = *(const float4*)&Bm[(size_t)(col0+jj)*K + k0 + kk0];
        Bs[kk0+0][jj] = t.x; Bs[kk0+1][jj] = t.y; Bs[kk0+2][jj] = t.z; Bs[kk0+3][jj] = t.w;
      }
    }
    __syncthreads();
    #pragma unroll
    for (int kk = 0; kk < 32; ++kk) {
      float4 bv = *(const float4*)&Bs[kk][tc];
      float av[RPT];
      if constexpr (RPT == 4) {
        float4 t = *(const float4*)&Ast[kk][tr];
        av[0] = t.x; av[1] = t.y; av[2] = t.z; av[3] = t.w;
      } else {
        av[0] = Ast[kk][tr]; av[1] = Ast[kk][tr+1];
      }
      #pragma unroll
      for (int i = 0; i < RPT; ++i) {
        acc[i][0] += av[i]*bv.x; acc[i][1] += av[i]*bv.y;
        acc[i][2] += av[i]*bv.z; acc[i][3] += av[i]*bv.w;
      }
    }
    __syncthreads();
  }
  float4 bb = {0,0,0,0};
  if (bias) bb = *(const float4*)&bias[m*JT + col0 + tc];
  float* Cp = C + (size_t)ks*NN*JT;
  #pragma unroll
  for (int i = 0; i < RPT; ++i) {
    float4 o = { acc[i][0]+bb.x, acc[i][1]+bb.y, acc[i][2]+bb.z, acc[i][3]+bb.w };
    *(float4*)&Cp[(size_t)(row0+tr+i)*JT + col0 + tc] = o;
  }
}

// ---------------- GAT scores (layer 1, H=4) ----------------
__global__ void k_scores4(const float* __restrict__ h, const float* __restrict__ a_s,
                          const float* __restrict__ a_d, float* __restrict__ es,
                          float* __restrict__ ed) {
  int gw = blockIdx.x*4 + (threadIdx.x >> 6);
  int lane = threadIdx.x & 63;
  if (gw >= NN*4) return;
  int n = gw >> 2, hh = gw & 3;
  int m = n >> 10;
  float v = h[(size_t)gw*64 + lane];
  float s = v * a_s[(m*4 + hh)*64 + lane];
  float d = v * a_d[(m*4 + hh)*64 + lane];
  #pragma unroll
  for (int off = 32; off; off >>= 1) { s += __shfl_xor(s, off); d += __shfl_xor(d, off); }
  if (lane == 0) { es[gw] = s; ed[gw] = d; }
}

// ---------------- GAT layer-2 partial combine + scores (H=1) ----------------
__global__ void k_scores1c(const float* __restrict__ pa, const float* __restrict__ pb,
                           const float* __restrict__ a_s, const float* __restrict__ a_d,
                           float* __restrict__ h2, float* __restrict__ es, float* __restrict__ ed) {
  int gw = blockIdx.x*4 + (threadIdx.x >> 6);
  int lane = threadIdx.x & 63;
  if (gw >= NN) return;
  int m = gw >> 10;
  size_t idx = (size_t)gw*64 + lane;
  float v = pa[idx] + pb[idx];
  h2[idx] = v;
  float s = v * a_s[m*64 + lane];
  float d = v * a_d[m*64 + lane];
  #pragma unroll
  for (int off = 32; off; off >>= 1) { s += __shfl_xor(s, off); d += __shfl_xor(d, off); }
  if (lane == 0) { es[gw] = s; ed[gw] = d; }
}

// ---------------- per-edge softmax numerator ----------------
template<int H>
__global__ void k_pexp(const int* __restrict__ src, const int* __restrict__ dst,
                       const int* __restrict__ epos, const float* __restrict__ es,
                       const float* __restrict__ ed, float* __restrict__ pval) {
  int t = blockIdx.x*256 + threadIdx.x;
  if (t >= EE*H) return;
  int e, hh;
  if (H == 4) { e = t >> 2; hh = t & 3; } else { e = t; hh = 0; }
  float v = __expf(lrelu(es[src[e]*H + hh] + ed[dst[e]*H + hh]));
  pval[(size_t)epos[e]*H + hh] = v;
}

// ---------------- GAT gather-aggregation ----------------
template<int H>
__global__ __launch_bounds__(256) void k_agg(const float* __restrict__ h,
    const float* __restrict__ es, const float* __restrict__ ed, const int* __restrict__ rs,
    const int* __restrict__ csr_src, const float* __restrict__ pval,
    const float* __restrict__ bias, float* __restrict__ out) {
  int gw = blockIdx.x*4 + (threadIdx.x >> 6);
  int lane = threadIdx.x & 63;
  if (gw >= NN*H) return;
  int n, hh;
  if (H == 4) { n = gw >> 2; hh = gw & 3; } else { n = gw; hh = 0; }
  int m = n >> 10;
  float p0 = __expf(lrelu(es[n*H + hh] + ed[n*H + hh]));   // self-loop
  float den = p0;
  float acc = p0 * h[(size_t)gw*64 + lane];
  int beg = rs[n], end = rs[n+1];
  for (int i = beg; i < end; ++i) {
    float pe = pval[(size_t)i*H + hh];
    int s = csr_src[i];
    den += pe;
    acc += pe * h[(size_t)(s*H + hh)*64 + lane];
  }
  float v = acc/den + bias[(m*H + hh)*64 + lane];
  out[(size_t)gw*64 + lane] = fmaxf(v, 0.f);
}

// ---------------- self-attention: lane=query, wave-uniform K/V via s_load ----------------
// grid = MODS*16*4*KC2 (m, qtile, head, kcg); block 256 = 4 waves = 4 key sub-chunks.
__global__ __launch_bounds__(256) void k_attn(const float* __restrict__ qkv,
    float* __restrict__ pd, float* __restrict__ pacc) {
  int b = blockIdx.x;
  int kcg = b & (KC2-1); b /= KC2;
  int h = b & 3; b >>= 2;
  int qt = b & 15; int m = b >> 4;
  int lane = threadIdx.x & 63;
  int wu = __builtin_amdgcn_readfirstlane(threadIdx.x >> 6);
  int n = m*NMOD + qt*64 + lane;
  float q[16];
  const float* qrow = qkv + (size_t)n*192 + h*16;
  #pragma unroll
  for (int c0 = 0; c0 < 16; c0 += 4) {
    float4 t = *(const float4*)(qrow + c0);
    q[c0] = t.x*0.25f; q[c0+1] = t.y*0.25f; q[c0+2] = t.z*0.25f; q[c0+3] = t.w*0.25f;
  }
  // this wave's 128 keys: wave-uniform base -> scalar loads
  const float* kb = qkv + (size_t)(m*NMOD + kcg*512 + wu*128)*192 + 64 + h*16;
  float den = 0.f, acc[16] = {};
  #pragma unroll 2
  for (int j = 0; j < 128; ++j) {
    const float* kr = kb + (size_t)j*192;
    float s0 = 0.f, s1 = 0.f, s2 = 0.f, s3 = 0.f;
    #pragma unroll
    for (int c = 0; c < 4; ++c) {
      s0 += q[c]*kr[c]; s1 += q[4+c]*kr[4+c]; s2 += q[8+c]*kr[8+c]; s3 += q[12+c]*kr[12+c];
    }
    float p = __expf((s0+s1)+(s2+s3));
    den += p;
    const float* vr = kr + 64;
    #pragma unroll
    for (int c = 0; c < 16; ++c) acc[c] += p*vr[c];
  }
  __shared__ float red[4][64][17];
  #pragma unroll
  for (int c = 0; c < 16; ++c) red[wu][lane][c] = acc[c];
  red[wu][lane][16] = den;
  __syncthreads();
  if (wu == 0) {
    size_t o = ((size_t)n*4 + h)*KC2 + kcg;
    float dt = red[0][lane][16] + red[1][lane][16] + red[2][lane][16] + red[3][lane][16];
    pd[o] = dt;
    #pragma unroll
    for (int c = 0; c < 16; ++c)
      pacc[o*16 + c] = red[0][lane][c] + red[1][lane][c] + red[2][lane][c] + red[3][lane][c];
  }
}

__global__ void k_attn_combine(const float* __restrict__ pd, const float* __restrict__ pacc,
                               float* __restrict__ attn) {
  int t = blockIdx.x*256 + threadIdx.x;   // (n, h)
  if (t >= NN*4) return;
  float inv = 1.f/(pd[(size_t)t*KC2] + pd[(size_t)t*KC2 + 1]);
  int n = t >> 2, h = t & 3;
  #pragma unroll
  for (int c = 0; c < 16; ++c)
    attn[(size_t)n*64 + h*16 + c] = (pacc[(size_t)t*32 + c] + pacc[(size_t)t*32 + 16 + c])*inv;
}

// ---------------- node-mean + folded output projection -> reps ----------------
__global__ void k_reps(const float* __restrict__ attn, const float* __restrict__ out_w,
                       const float* __restrict__ out_b, float* __restrict__ reps,
                       float* __restrict__ dout) {
  int m = blockIdx.x;
  __shared__ float part[4][64];
  __shared__ float abar[64];
  int c = threadIdx.x & 63, pp = threadIdx.x >> 6;
  float s = 0.f;
  const float* base = attn + (size_t)m*NMOD*64;
  for (int i = pp*256; i < pp*256 + 256; ++i) s += base[(size_t)i*64 + c];
  part[pp][c] = s;
  __syncthreads();
  if (pp == 0) abar[c] = (part[0][c]+part[1][c]+part[2][c]+part[3][c]) * (1.f/NMOD);
  __syncthreads();
  if (threadIdx.x < 64) {
    int j = threadIdx.x;
    float r = out_b[m*64 + j];
    const float* wr = out_w + (size_t)m*64*64 + (size_t)j*64;
    #pragma unroll
    for (int k = 0; k < 64; ++k) r += abar[k]*wr[k];
    reps[m*64 + j] = r;
    dout[2 + m*64 + j] = r;     // Output 1
  }
}

// ---------------- cross-attention + fusion + classifier (single block) ----------------
__global__ __launch_bounds__(256) void k_final(const float* __restrict__ reps,
    const float* __restrict__ ca_in_w, const float* __restrict__ ca_in_b,
    const float* __restrict__ ca_out_w, const float* __restrict__ ca_out_b,
    const float* __restrict__ fusion_w, const float* __restrict__ fc_w,
    const float* __restrict__ fc_b, const float* __restrict__ c1_w,
    const float* __restrict__ c1_b, const float* __restrict__ c2_w,
    const float* __restrict__ c2_b, float* __restrict__ dout) {
  __shared__ float R[7][64];
  __shared__ float QKV[7][192];
  __shared__ float alpha[4][7][7];
  __shared__ float O[7][64];
  __shared__ float CR[7][64];
  __shared__ float W[7];
  __shared__ float FU[64];
  __shared__ float HM[32];
  int tid = threadIdx.x;
  for (int i = tid; i < 7*64; i += 256) R[i/64][i%64] = reps[i];
  __syncthreads();
  for (int i = tid; i < 7*192; i += 256) {
    int r = i/192, j = i - r*192;
    float s = ca_in_b[j];
    for (int k = 0; k < 64; ++k) s += R[r][k]*ca_in_w[j*64 + k];
    QKV[r][j] = s;
  }
  __syncthreads();
  if (tid < 28) {
    int hh = tid/7, qi = tid - hh*7;
    float p[7]; float den = 0.f;
    for (int ki = 0; ki < 7; ++ki) {
      float s = 0.f;
      for (int c = 0; c < 16; ++c) s += QKV[qi][hh*16+c]*QKV[ki][64 + hh*16 + c];
      p[ki] = __expf(s*0.25f);
      den += p[ki];
    }
    for (int ki = 0; ki < 7; ++ki) alpha[hh][qi][ki] = p[ki]/den;
  }
  __syncthreads();
  for (int i = tid; i < 7*64; i += 256) {
    int qi = i/64, j = i - qi*64;
    int hh = j >> 4;
    float s = 0.f;
    for (int ki = 0; ki < 7; ++ki) s += alpha[hh][qi][ki]*QKV[ki][128 + j];
    O[qi][j] = s;
  }
  __syncthreads();
  for (int i = tid; i < 7*64; i += 256) {
    int qi = i/64, j = i - qi*64;
    float s = ca_out_b[j];
    for (int k = 0; k < 64; ++k) s += O[qi][k]*ca_out_w[j*64 + k];
    CR[qi][j] = s;
  }
  if (tid == 0) {
    float p[7]; float den = 0.f;
    for (int i = 0; i < 7; ++i) { p[i] = __expf(fusion_w[i]); den += p[i]; }
    for (int i = 0; i < 7; ++i) W[i] = p[i]/den;
  }
  __syncthreads();
  if (tid < 64) {
    float s = fc_b[tid];
    for (int i = 0; i < 448; ++i) s += CR[i>>6][i&63]*W[i>>6]*fc_w[(size_t)i*64 + tid];
    FU[tid] = s;
  }
  __syncthreads();
  if (tid < 32) {
    float s = c1_b[tid];
    for (int k = 0; k < 64; ++k) s += FU[k]*c1_w[k*32 + tid];
    HM[tid] = fmaxf(s, 0.f);
  }
  __syncthreads();
  if (tid < 2) {
    float s = c2_b[tid];
    for (int k = 0; k < 32; ++k) s += HM[k]*c2_w[k*2 + tid];
    dout[tid] = s;              // Output 0
  }
}

extern "C" void kernel_launch(void* const* d_in, const int* in_sizes, int n_in,
                              void* d_out, int out_size, void* d_ws, size_t ws_size,
                              hipStream_t stream) {
  (void)in_sizes; (void)n_in; (void)out_size; (void)ws_size;
  const float* x       = (const float*)d_in[0];
  const int*   ei      = (const int*)d_in[1];
  const float* g1_w    = (const float*)d_in[3];
  const float* g1_as   = (const float*)d_in[4];
  const float* g1_ad   = (const float*)d_in[5];
  const float* g1_b    = (const float*)d_in[6];
  const float* g2_w    = (const float*)d_in[7];
  const float* g2_as   = (const float*)d_in[8];
  const float* g2_ad   = (const float*)d_in[9];
  const float* g2_b    = (const float*)d_in[10];
  const float* sa_in_w = (const float*)d_in[11];
  const float* sa_in_b = (const float*)d_in[12];
  const float* sa_out_w= (const float*)d_in[13];
  const float* sa_out_b= (const float*)d_in[14];
  const float* ca_in_w = (const float*)d_in[15];
  const float* ca_in_b = (const float*)d_in[16];
  const float* ca_out_w= (const float*)d_in[17];
  const float* ca_out_b= (const float*)d_in[18];
  const float* fusion_w= (const float*)d_in[19];
  const float* fc_w    = (const float*)d_in[20];
  const float* fc_b    = (const float*)d_in[21];
  const float* c1_w    = (const float*)d_in[22];
  const float* c1_b    = (const float*)d_in[23];
  const float* c2_w    = (const float*)d_in[24];
  const float* c2_b    = (const float*)d_in[25];
  float* dout = (float*)d_out;

  const int* src = ei;        // edge_index[0]
  const int* dst = ei + EE;   // edge_index[1]

  // ---- workspace carve (aliasing by lifetime) ----
  char* p = (char*)d_ws;
  int* cnt     = (int*)p; p += (size_t)NN*sizeof(int);
  int* fill    = (int*)p; p += (size_t)NN*sizeof(int);
  int* rs      = (int*)p; p += (size_t)(NN+4)*sizeof(int);
  int* epos    = (int*)p; p += (size_t)EE*sizeof(int);
  int* csr_src = (int*)p; p += (size_t)EE*sizeof(int);
  p = (char*)(((uintptr_t)p + 255) & ~(uintptr_t)255);
  float* h1   = (float*)p; p += (size_t)NN*256*4;   // then: h2 partials (2x NN*64), then qkv (NN*192)
  float* es1  = (float*)p; p += (size_t)NN*4*4;
  float* ed1  = (float*)p; p += (size_t)NN*4*4;
  float* gat1 = (float*)p; p += (size_t)NN*256*4;   // then: pd + pacc
  float* h2   = (float*)p; p += (size_t)NN*64*4;    // pval1 spans h2..z before they're written
  float* es2  = (float*)p; p += (size_t)NN*4;
  float* ed2  = (float*)p; p += (size_t)NN*4;
  float* z    = (float*)p; p += (size_t)NN*64*4;
  float* attn = (float*)p; p += (size_t)NN*64*4;    // pval2 before attn written
  float* reps = (float*)p; p += (size_t)MODS*64*4;
  float* pval1 = h2;                 // EE*4 floats; dead before h2/es2/ed2/z written
  float* pval2 = attn;               // EE floats; dead before attn written
  float* h2a   = h1;                 // K-split partials; h1 dead after k_agg<4>
  float* h2b   = h1 + (size_t)NN*64;
  float* qkv   = h1;                 // h2a/h2b dead after k_scores1c
  float* pd    = gat1;               // gat1 dead after k_gemm (layer2)
  float* pacc  = gat1 + (size_t)NN*4*KC2;

  hipMemsetAsync(cnt, 0, 2*(size_t)NN*sizeof(int), stream);   // cnt + fill
  k_count<<<(EE+255)/256, 256, 0, stream>>>(dst, cnt);
  k_scan<<<1, 1024, 0, stream>>>(cnt, rs);
  k_fill<<<(EE+255)/256, 256, 0, stream>>>(src, dst, rs, fill, csr_src, epos);

  // GAT layer 1
  k_gemm<128,256,false,64,1><<<MODS*16*4, 256, 0, stream>>>(x, g1_w, nullptr, h1);
  k_scores4<<<NN, 256, 0, stream>>>(h1, g1_as, g1_ad, es1, ed1);
  k_pexp<4><<<(EE*4+255)/256, 256, 0, stream>>>(src, dst, epos, es1, ed1, pval1);
  k_agg<4><<<NN, 256, 0, stream>>>(h1, es1, ed1, rs, csr_src, pval1, g1_b, gat1);

  // GAT layer 2 (K-split 2, combine fused into scores)
  k_gemm<256,64,false,32,2><<<MODS*32*2, 256, 0, stream>>>(gat1, g2_w, nullptr, h2a);
  k_scores1c<<<NN/4, 256, 0, stream>>>(h2a, h2b, g2_as, g2_ad, h2, es2, ed2);
  k_pexp<1><<<(EE+255)/256, 256, 0, stream>>>(src, dst, epos, es2, ed2, pval2);
  k_agg<1><<<NN/4, 256, 0, stream>>>(h2, es2, ed2, rs, csr_src, pval2, g2_b, z);

  // self-attention
  k_gemm<64,192,true,64,1><<<MODS*16*3, 256, 0, stream>>>(z, sa_in_w, sa_in_b, qkv);
  k_attn<<<MODS*16*4*KC2, 256, 0, stream>>>(qkv, pd, pacc);
  k_attn_combine<<<(NN*4+255)/256, 256, 0, stream>>>(pd, pacc, attn);

  // reps (Output 1), then head (Output 0)
  k_reps<<<MODS, 256, 0, stream>>>(attn, sa_out_w, sa_out_b, reps, dout);
  k_final<<<1, 256, 0, stream>>>(reps, ca_in_w, ca_in_b, ca_out_w, ca_out_b,
                                 fusion_w, fc_w, fc_b, c1_w, c1_b, c2_w, c2_b, dout);
}

// Round 3
// 209.533 us; speedup vs baseline: 1.6727x; 1.2288x over previous
//
#include <hip/hip_runtime.h>
#include <hip/hip_bf16.h>
#include <stdint.h>

#define MODS 7
#define NMOD 1024
#define EMOD 32768
#define NN (MODS*NMOD)   // 7168 nodes
#define EE (MODS*EMOD)   // 229376 edges
#define KC2 2            // block-level key chunks for self-attention

typedef __hip_bfloat16 bf16;

static __device__ __forceinline__ float lrelu(float x){ return x > 0.f ? x : 0.2f*x; }

// ---------------- CSR build ----------------
__global__ void k_count(const int* __restrict__ dst, int* __restrict__ cnt) {
  int e = blockIdx.x*256 + threadIdx.x;
  if (e < EE) atomicAdd(&cnt[dst[e]], 1);
}

__global__ void k_scan(const int* __restrict__ cnt, int* __restrict__ rs) {
  __shared__ int wsum[16];
  __shared__ int carry;
  int tid = threadIdx.x, lane = tid & 63, wid = tid >> 6;
  if (tid == 0) carry = 0;
  __syncthreads();
  for (int base = 0; base < NN; base += 1024) {
    int i = base + tid;
    int v = (i < NN) ? cnt[i] : 0;
    int x = v;
    #pragma unroll
    for (int off = 1; off < 64; off <<= 1) { int t = __shfl_up(x, off); if (lane >= off) x += t; }
    if (lane == 63) wsum[wid] = x;
    __syncthreads();
    if (wid == 0 && lane < 16) {
      int y = wsum[lane];
      #pragma unroll
      for (int off = 1; off < 16; off <<= 1) { int t = __shfl_up(y, off, 16); if (lane >= off) y += t; }
      wsum[lane] = y;
    }
    __syncthreads();
    int woff = wid ? wsum[wid-1] : 0;
    int c = carry;
    if (i < NN) rs[i] = x - v + woff + c;   // exclusive
    __syncthreads();
    if (tid == 0) carry += wsum[15];
    __syncthreads();
  }
  if (threadIdx.x == 0) rs[NN] = carry;
}

__global__ void k_fill(const int* __restrict__ src, const int* __restrict__ dst,
                       const int* __restrict__ rs, int* __restrict__ fill,
                       int* __restrict__ csr_src) {
  int e = blockIdx.x*256 + threadIdx.x;
  if (e < EE) {
    int d = dst[e];
    int pos = rs[d] + atomicAdd(&fill[d], 1);
    csr_src[pos] = src[e];
  }
}

// ---------------- per-module SGEMM, vectorized LDS, optional bf16 output ----------------
template<int K, int JT, bool TB, int RT, int KS, bool OBF>
__global__ __launch_bounds__(256) void k_gemm(const float* __restrict__ A,
    const float* __restrict__ B, const float* __restrict__ bias, void* __restrict__ Cv) {
  constexpr int jt = JT/64;
  constexpr int rtiles = NMOD/RT;
  constexpr int RPT = RT/16;
  constexpr int KCHUNK = K/KS;
  int b = blockIdx.x;
  int ks = b % KS; b /= KS;
  int ct = b % jt; b /= jt;
  int rt = b % rtiles; b /= rtiles;
  int m = b;
  int row0 = m*NMOD + rt*RT;
  int col0 = ct*64;
  __shared__ float Ast[32][RT+4];  // transposed: [kk][row]
  __shared__ float Bs[32][68];
  float acc[RPT][4] = {};
  int tid = threadIdx.x;
  int tr = (tid >> 4) * RPT;
  int tc = (tid & 15) * 4;
  const float* Bm = B + (size_t)m*K*JT;
  for (int k0 = ks*KCHUNK; k0 < (ks+1)*KCHUNK; k0 += 32) {
    constexpr int ANUM = RT*32/1024;
    #pragma unroll
    for (int i = 0; i < ANUM; ++i) {
      int it = tid + i*256;
      int rr = it >> 3, kk0 = (it & 7)*4;
      float4 t = *(const float4*)&A[(size_t)(row0+rr)*K + k0 + kk0];
      Ast[kk0+0][rr] = t.x; Ast[kk0+1][rr] = t.y; Ast[kk0+2][rr] = t.z; Ast[kk0+3][rr] = t.w;
    }
    #pragma unroll
    for (int i = 0; i < 2; ++i) {
      int it = tid + i*256;
      if (!TB) {
        int kk = it >> 4, jj0 = (it & 15)*4;
        float4 t = *(const float4*)&Bm[(size_t)(k0+kk)*JT + col0 + jj0];
        Bs[kk][jj0] = t.x; Bs[kk][jj0+1] = t.y; Bs[kk][jj0+2] = t.z; Bs[kk][jj0+3] = t.w;
      } else {
        int jj = it >> 3, kk0 = (it & 7)*4;
        float4 t = *(const float4*)&Bm[(size_t)(col0+jj)*K + k0 + kk0];
        Bs[kk0+0][jj] = t.x; Bs[kk0+1][jj] = t.y; Bs[kk0+2][jj] = t.z; Bs[kk0+3][jj] = t.w;
      }
    }
    __syncthreads();
    #pragma unroll
    for (int kk = 0; kk < 32; ++kk) {
      float4 bv = *(const float4*)&Bs[kk][tc];
      float av[RPT];
      if constexpr (RPT == 4) {
        float4 t = *(const float4*)&Ast[kk][tr];
        av[0] = t.x; av[1] = t.y; av[2] = t.z; av[3] = t.w;
      } else {
        av[0] = Ast[kk][tr]; av[1] = Ast[kk][tr+1];
      }
      #pragma unroll
      for (int i = 0; i < RPT; ++i) {
        acc[i][0] += av[i]*bv.x; acc[i][1] += av[i]*bv.y;
        acc[i][2] += av[i]*bv.z; acc[i][3] += av[i]*bv.w;
      }
    }
    __syncthreads();
  }
  float4 bb = {0,0,0,0};
  if (bias) bb = *(const float4*)&bias[m*JT + col0 + tc];
  #pragma unroll
  for (int i = 0; i < RPT; ++i) {
    float4 o = { acc[i][0]+bb.x, acc[i][1]+bb.y, acc[i][2]+bb.z, acc[i][3]+bb.w };
    size_t idx = (size_t)(row0+tr+i)*JT + col0 + tc;
    if constexpr (OBF) {
      bf16* Cp = (bf16*)Cv;
      bf16 tmp[4] = { __float2bfloat16(o.x), __float2bfloat16(o.y),
                      __float2bfloat16(o.z), __float2bfloat16(o.w) };
      *(uint2*)&Cp[idx] = *(const uint2*)tmp;
    } else {
      float* Cp = (float*)Cv + (size_t)ks*NN*JT;
      *(float4*)&Cp[idx] = o;
    }
  }
}

// ---------------- GAT scores (layer 1, H=4), bf16 h ----------------
__global__ void k_scores4(const bf16* __restrict__ h, const float* __restrict__ a_s,
                          const float* __restrict__ a_d, float* __restrict__ es,
                          float* __restrict__ ed) {
  int gw = blockIdx.x*4 + (threadIdx.x >> 6);
  int lane = threadIdx.x & 63;
  if (gw >= NN*4) return;
  int n = gw >> 2, hh = gw & 3;
  int m = n >> 10;
  float v = __bfloat162float(h[(size_t)gw*64 + lane]);
  float s = v * a_s[(m*4 + hh)*64 + lane];
  float d = v * a_d[(m*4 + hh)*64 + lane];
  #pragma unroll
  for (int off = 32; off; off >>= 1) { s += __shfl_xor(s, off); d += __shfl_xor(d, off); }
  if (lane == 0) { es[gw] = s; ed[gw] = d; }
}

// ---------------- GAT layer-2 partial combine + scores (H=1); writes bf16 h2 ----------------
__global__ void k_scores1c(const float* __restrict__ pa, const float* __restrict__ pb,
                           const float* __restrict__ a_s, const float* __restrict__ a_d,
                           bf16* __restrict__ h2, float* __restrict__ es, float* __restrict__ ed) {
  int gw = blockIdx.x*4 + (threadIdx.x >> 6);
  int lane = threadIdx.x & 63;
  if (gw >= NN) return;
  int m = gw >> 10;
  size_t idx = (size_t)gw*64 + lane;
  float v = pa[idx] + pb[idx];
  h2[idx] = __float2bfloat16(v);
  float s = v * a_s[m*64 + lane];
  float d = v * a_d[m*64 + lane];
  #pragma unroll
  for (int off = 32; off; off >>= 1) { s += __shfl_xor(s, off); d += __shfl_xor(d, off); }
  if (lane == 0) { es[gw] = s; ed[gw] = d; }
}

// ---------------- GAT gather-aggregation: bf16 h, inline exp, 4-wide pipelined ----------------
template<int H>
__global__ __launch_bounds__(256) void k_agg(const bf16* __restrict__ h,
    const float* __restrict__ es, const float* __restrict__ ed, const int* __restrict__ rs,
    const int* __restrict__ csr_src, const float* __restrict__ bias, float* __restrict__ out) {
  int gw = blockIdx.x*4 + (threadIdx.x >> 6);
  int lane = threadIdx.x & 63;
  if (gw >= NN*H) return;
  int n, hh;
  if (H == 4) { n = gw >> 2; hh = gw & 3; } else { n = gw; hh = 0; }
  int m = n >> 10;
  float edv = ed[gw];
  float p0 = __expf(lrelu(es[gw] + edv));   // self-loop
  float den = p0;
  float acc = p0 * __bfloat162float(h[(size_t)gw*64 + lane]);
  int beg = rs[n], end = rs[n+1];
  int i = beg;
  for (; i + 4 <= end; i += 4) {
    int s0 = csr_src[i], s1 = csr_src[i+1], s2 = csr_src[i+2], s3 = csr_src[i+3];
    float e0 = es[s0*H + hh], e1 = es[s1*H + hh], e2 = es[s2*H + hh], e3 = es[s3*H + hh];
    float v0 = __bfloat162float(h[((size_t)s0*H + hh)*64 + lane]);
    float v1 = __bfloat162float(h[((size_t)s1*H + hh)*64 + lane]);
    float v2 = __bfloat162float(h[((size_t)s2*H + hh)*64 + lane]);
    float v3 = __bfloat162float(h[((size_t)s3*H + hh)*64 + lane]);
    float q0 = __expf(lrelu(e0 + edv));
    float q1 = __expf(lrelu(e1 + edv));
    float q2 = __expf(lrelu(e2 + edv));
    float q3 = __expf(lrelu(e3 + edv));
    den += (q0 + q1) + (q2 + q3);
    acc += q0*v0; acc += q1*v1; acc += q2*v2; acc += q3*v3;
  }
  for (; i < end; ++i) {
    int s = csr_src[i];
    float q = __expf(lrelu(es[s*H + hh] + edv));
    den += q;
    acc += q * __bfloat162float(h[((size_t)s*H + hh)*64 + lane]);
  }
  float v = acc/den + bias[(m*H + hh)*64 + lane];
  out[(size_t)gw*64 + lane] = fmaxf(v, 0.f);
}

// ---------------- self-attention: lane=query, wave-uniform K/V via s_load ----------------
__global__ __launch_bounds__(256) void k_attn(const float* __restrict__ qkv,
    float* __restrict__ pd, float* __restrict__ pacc) {
  int b = blockIdx.x;
  int kcg = b & (KC2-1); b /= KC2;
  int h = b & 3; b >>= 2;
  int qt = b & 15; int m = b >> 4;
  int lane = threadIdx.x & 63;
  int wu = __builtin_amdgcn_readfirstlane(threadIdx.x >> 6);
  int n = m*NMOD + qt*64 + lane;
  float q[16];
  const float* qrow = qkv + (size_t)n*192 + h*16;
  #pragma unroll
  for (int c0 = 0; c0 < 16; c0 += 4) {
    float4 t = *(const float4*)(qrow + c0);
    q[c0] = t.x*0.25f; q[c0+1] = t.y*0.25f; q[c0+2] = t.z*0.25f; q[c0+3] = t.w*0.25f;
  }
  const float* kb = qkv + (size_t)(m*NMOD + kcg*512 + wu*128)*192 + 64 + h*16;
  float den = 0.f, acc[16] = {};
  #pragma unroll 2
  for (int j = 0; j < 128; ++j) {
    const float* kr = kb + (size_t)j*192;
    float s0 = 0.f, s1 = 0.f, s2 = 0.f, s3 = 0.f;
    #pragma unroll
    for (int c = 0; c < 4; ++c) {
      s0 += q[c]*kr[c]; s1 += q[4+c]*kr[4+c]; s2 += q[8+c]*kr[8+c]; s3 += q[12+c]*kr[12+c];
    }
    float p = __expf((s0+s1)+(s2+s3));
    den += p;
    const float* vr = kr + 64;
    #pragma unroll
    for (int c = 0; c < 16; ++c) acc[c] += p*vr[c];
  }
  __shared__ float red[4][64][17];
  #pragma unroll
  for (int c = 0; c < 16; ++c) red[wu][lane][c] = acc[c];
  red[wu][lane][16] = den;
  __syncthreads();
  if (wu == 0) {
    size_t o = ((size_t)n*4 + h)*KC2 + kcg;
    float dt = red[0][lane][16] + red[1][lane][16] + red[2][lane][16] + red[3][lane][16];
    pd[o] = dt;
    #pragma unroll
    for (int c = 0; c < 16; ++c)
      pacc[o*16 + c] = red[0][lane][c] + red[1][lane][c] + red[2][lane][c] + red[3][lane][c];
  }
}

__global__ void k_attn_combine(const float* __restrict__ pd, const float* __restrict__ pacc,
                               float* __restrict__ attn) {
  int t = blockIdx.x*256 + threadIdx.x;   // (n, h)
  if (t >= NN*4) return;
  float inv = 1.f/(pd[(size_t)t*KC2] + pd[(size_t)t*KC2 + 1]);
  int n = t >> 2, h = t & 3;
  #pragma unroll
  for (int c = 0; c < 16; ++c)
    attn[(size_t)n*64 + h*16 + c] = (pacc[(size_t)t*32 + c] + pacc[(size_t)t*32 + 16 + c])*inv;
}

// ---------------- node-mean + folded output projection -> reps ----------------
__global__ void k_reps(const float* __restrict__ attn, const float* __restrict__ out_w,
                       const float* __restrict__ out_b, float* __restrict__ reps,
                       float* __restrict__ dout) {
  int m = blockIdx.x;
  __shared__ float part[4][64];
  __shared__ float abar[64];
  int c = threadIdx.x & 63, pp = threadIdx.x >> 6;
  float s = 0.f;
  const float* base = attn + (size_t)m*NMOD*64;
  for (int i = pp*256; i < pp*256 + 256; ++i) s += base[(size_t)i*64 + c];
  part[pp][c] = s;
  __syncthreads();
  if (pp == 0) abar[c] = (part[0][c]+part[1][c]+part[2][c]+part[3][c]) * (1.f/NMOD);
  __syncthreads();
  if (threadIdx.x < 64) {
    int j = threadIdx.x;
    float r = out_b[m*64 + j];
    const float* wr = out_w + (size_t)m*64*64 + (size_t)j*64;
    #pragma unroll
    for (int k = 0; k < 64; ++k) r += abar[k]*wr[k];
    reps[m*64 + j] = r;
    dout[2 + m*64 + j] = r;     // Output 1
  }
}

// ---------------- cross-attention + fusion + classifier (single block) ----------------
__global__ __launch_bounds__(256) void k_final(const float* __restrict__ reps,
    const float* __restrict__ ca_in_w, const float* __restrict__ ca_in_b,
    const float* __restrict__ ca_out_w, const float* __restrict__ ca_out_b,
    const float* __restrict__ fusion_w, const float* __restrict__ fc_w,
    const float* __restrict__ fc_b, const float* __restrict__ c1_w,
    const float* __restrict__ c1_b, const float* __restrict__ c2_w,
    const float* __restrict__ c2_b, float* __restrict__ dout) {
  __shared__ float R[7][64];
  __shared__ float QKV[7][192];
  __shared__ float alpha[4][7][7];
  __shared__ float O[7][64];
  __shared__ float CR[7][64];
  __shared__ float W[7];
  __shared__ float FU[64];
  __shared__ float HM[32];
  int tid = threadIdx.x;
  for (int i = tid; i < 7*64; i += 256) R[i/64][i%64] = reps[i];
  __syncthreads();
  for (int i = tid; i < 7*192; i += 256) {
    int r = i/192, j = i - r*192;
    float s = ca_in_b[j];
    for (int k = 0; k < 64; ++k) s += R[r][k]*ca_in_w[j*64 + k];
    QKV[r][j] = s;
  }
  __syncthreads();
  if (tid < 28) {
    int hh = tid/7, qi = tid - hh*7;
    float p[7]; float den = 0.f;
    for (int ki = 0; ki < 7; ++ki) {
      float s = 0.f;
      for (int c = 0; c < 16; ++c) s += QKV[qi][hh*16+c]*QKV[ki][64 + hh*16 + c];
      p[ki] = __expf(s*0.25f);
      den += p[ki];
    }
    for (int ki = 0; ki < 7; ++ki) alpha[hh][qi][ki] = p[ki]/den;
  }
  __syncthreads();
  for (int i = tid; i < 7*64; i += 256) {
    int qi = i/64, j = i - qi*64;
    int hh = j >> 4;
    float s = 0.f;
    for (int ki = 0; ki < 7; ++ki) s += alpha[hh][qi][ki]*QKV[ki][128 + j];
    O[qi][j] = s;
  }
  __syncthreads();
  for (int i = tid; i < 7*64; i += 256) {
    int qi = i/64, j = i - qi*64;
    float s = ca_out_b[j];
    for (int k = 0; k < 64; ++k) s += O[qi][k]*ca_out_w[j*64 + k];
    CR[qi][j] = s;
  }
  if (tid == 0) {
    float p[7]; float den = 0.f;
    for (int i = 0; i < 7; ++i) { p[i] = __expf(fusion_w[i]); den += p[i]; }
    for (int i = 0; i < 7; ++i) W[i] = p[i]/den;
  }
  __syncthreads();
  if (tid < 64) {
    float s = fc_b[tid];
    for (int i = 0; i < 448; ++i) s += CR[i>>6][i&63]*W[i>>6]*fc_w[(size_t)i*64 + tid];
    FU[tid] = s;
  }
  __syncthreads();
  if (tid < 32) {
    float s = c1_b[tid];
    for (int k = 0; k < 64; ++k) s += FU[k]*c1_w[k*32 + tid];
    HM[tid] = fmaxf(s, 0.f);
  }
  __syncthreads();
  if (tid < 2) {
    float s = c2_b[tid];
    for (int k = 0; k < 32; ++k) s += HM[k]*c2_w[k*2 + tid];
    dout[tid] = s;              // Output 0
  }
}

extern "C" void kernel_launch(void* const* d_in, const int* in_sizes, int n_in,
                              void* d_out, int out_size, void* d_ws, size_t ws_size,
                              hipStream_t stream) {
  (void)in_sizes; (void)n_in; (void)out_size; (void)ws_size;
  const float* x       = (const float*)d_in[0];
  const int*   ei      = (const int*)d_in[1];
  const float* g1_w    = (const float*)d_in[3];
  const float* g1_as   = (const float*)d_in[4];
  const float* g1_ad   = (const float*)d_in[5];
  const float* g1_b    = (const float*)d_in[6];
  const float* g2_w    = (const float*)d_in[7];
  const float* g2_as   = (const float*)d_in[8];
  const float* g2_ad   = (const float*)d_in[9];
  const float* g2_b    = (const float*)d_in[10];
  const float* sa_in_w = (const float*)d_in[11];
  const float* sa_in_b = (const float*)d_in[12];
  const float* sa_out_w= (const float*)d_in[13];
  const float* sa_out_b= (const float*)d_in[14];
  const float* ca_in_w = (const float*)d_in[15];
  const float* ca_in_b = (const float*)d_in[16];
  const float* ca_out_w= (const float*)d_in[17];
  const float* ca_out_b= (const float*)d_in[18];
  const float* fusion_w= (const float*)d_in[19];
  const float* fc_w    = (const float*)d_in[20];
  const float* fc_b    = (const float*)d_in[21];
  const float* c1_w    = (const float*)d_in[22];
  const float* c1_b    = (const float*)d_in[23];
  const float* c2_w    = (const float*)d_in[24];
  const float* c2_b    = (const float*)d_in[25];
  float* dout = (float*)d_out;

  const int* src = ei;        // edge_index[0]
  const int* dst = ei + EE;   // edge_index[1]

  // ---- workspace carve (aliasing by lifetime) ----
  char* p = (char*)d_ws;
  int* cnt     = (int*)p; p += (size_t)NN*sizeof(int);
  int* fill    = (int*)p; p += (size_t)NN*sizeof(int);
  int* rs      = (int*)p; p += (size_t)(NN+4)*sizeof(int);
  int* csr_src = (int*)p; p += (size_t)EE*sizeof(int);
  p = (char*)(((uintptr_t)p + 255) & ~(uintptr_t)255);
  float* h1f  = (float*)p; p += (size_t)NN*256*4;   // bf16 h1; later h2 partials (2x NN*64 f32), then qkv (NN*192 f32)
  float* es1  = (float*)p; p += (size_t)NN*4*4;
  float* ed1  = (float*)p; p += (size_t)NN*4*4;
  float* gat1 = (float*)p; p += (size_t)NN*256*4;   // later: pd + pacc
  float* h2f  = (float*)p; p += (size_t)NN*64*4;    // bf16 h2
  float* es2  = (float*)p; p += (size_t)NN*4;
  float* ed2  = (float*)p; p += (size_t)NN*4;
  float* z    = (float*)p; p += (size_t)NN*64*4;
  float* attn = (float*)p; p += (size_t)NN*64*4;
  float* reps = (float*)p; p += (size_t)MODS*64*4;
  bf16* h1    = (bf16*)h1f;
  bf16* h2    = (bf16*)h2f;
  float* h2a  = h1f;                 // K-split partials; h1 dead after k_agg<4>
  float* h2b  = h1f + (size_t)NN*64;
  float* qkv  = h1f;                 // h2a/h2b dead after k_scores1c
  float* pd   = gat1;                // gat1 dead after layer-2 gemm
  float* pacc = gat1 + (size_t)NN*4*KC2;

  hipMemsetAsync(cnt, 0, 2*(size_t)NN*sizeof(int), stream);   // cnt + fill
  k_count<<<(EE+255)/256, 256, 0, stream>>>(dst, cnt);
  k_scan<<<1, 1024, 0, stream>>>(cnt, rs);
  k_fill<<<(EE+255)/256, 256, 0, stream>>>(src, dst, rs, fill, csr_src);

  // GAT layer 1 (h1 in bf16)
  k_gemm<128,256,false,64,1,true><<<MODS*16*4, 256, 0, stream>>>(x, g1_w, nullptr, h1);
  k_scores4<<<NN, 256, 0, stream>>>(h1, g1_as, g1_ad, es1, ed1);
  k_agg<4><<<NN, 256, 0, stream>>>(h1, es1, ed1, rs, csr_src, g1_b, gat1);

  // GAT layer 2 (K-split 2; combine + scores fused; h2 in bf16)
  k_gemm<256,64,false,32,2,false><<<MODS*32*2, 256, 0, stream>>>(gat1, g2_w, nullptr, h2a);
  k_scores1c<<<NN/4, 256, 0, stream>>>(h2a, h2b, g2_as, g2_ad, h2, es2, ed2);
  k_agg<1><<<NN/4, 256, 0, stream>>>(h2, es2, ed2, rs, csr_src, g2_b, z);

  // self-attention
  k_gemm<64,192,true,64,1,false><<<MODS*16*3, 256, 0, stream>>>(z, sa_in_w, sa_in_b, qkv);
  k_attn<<<MODS*16*4*KC2, 256, 0, stream>>>(qkv, pd, pacc);
  k_attn_combine<<<(NN*4+255)/256, 256, 0, stream>>>(pd, pacc, attn);

  // reps (Output 1), then head (Output 0)
  k_reps<<<MODS, 256, 0, stream>>>(attn, sa_out_w, sa_out_b, reps, dout);
  k_final<<<1, 256, 0, stream>>>(reps, ca_in_w, ca_in_b, ca_out_w, ca_out_b,
                                 fusion_w, fc_w, fc_b, c1_w, c1_b, c2_w, c2_b, dout);
}

// Round 4
// 175.091 us; speedup vs baseline: 2.0017x; 1.1967x over previous
//
#include <hip/hip_runtime.h>
#include <hip/hip_bf16.h>
#include <stdint.h>

#define MODS 7
#define NMOD 1024
#define EMOD 32768
#define NN (MODS*NMOD)   // 7168 nodes
#define EE (MODS*EMOD)   // 229376 edges
#define KC2 4            // block-level key chunks for self-attention

typedef __hip_bfloat16 bf16;

static __device__ __forceinline__ float lrelu(float x){ return x > 0.f ? x : 0.2f*x; }
static __device__ __forceinline__ float bfu(unsigned short u){ return __uint_as_float(((unsigned)u) << 16); }
static __device__ __forceinline__ float2 f2fma(float2 a, float2 b, float2 c){
  return make_float2(fmaf(a.x,b.x,c.x), fmaf(a.y,b.y,c.y));
}

// ---------------- CSR build ----------------
__global__ void k_count(const int* __restrict__ dst, int* __restrict__ cnt) {
  int e = blockIdx.x*256 + threadIdx.x;
  if (e < EE) atomicAdd(&cnt[dst[e]], 1);
}

__global__ void k_scan(const int* __restrict__ cnt, int* __restrict__ rs) {
  __shared__ int wsum[16];
  __shared__ int carry;
  int tid = threadIdx.x, lane = tid & 63, wid = tid >> 6;
  if (tid == 0) carry = 0;
  __syncthreads();
  for (int base = 0; base < NN; base += 1024) {
    int i = base + tid;
    int v = (i < NN) ? cnt[i] : 0;
    int x = v;
    #pragma unroll
    for (int off = 1; off < 64; off <<= 1) { int t = __shfl_up(x, off); if (lane >= off) x += t; }
    if (lane == 63) wsum[wid] = x;
    __syncthreads();
    if (wid == 0 && lane < 16) {
      int y = wsum[lane];
      #pragma unroll
      for (int off = 1; off < 16; off <<= 1) { int t = __shfl_up(y, off, 16); if (lane >= off) y += t; }
      wsum[lane] = y;
    }
    __syncthreads();
    int woff = wid ? wsum[wid-1] : 0;
    int c = carry;
    if (i < NN) rs[i] = x - v + woff + c;   // exclusive
    __syncthreads();
    if (tid == 0) carry += wsum[15];
    __syncthreads();
  }
  if (threadIdx.x == 0) rs[NN] = carry;
}

__global__ void k_fill(const int* __restrict__ src, const int* __restrict__ dst,
                       const int* __restrict__ rs, int* __restrict__ fill,
                       int* __restrict__ csr_src) {
  int e = blockIdx.x*256 + threadIdx.x;
  if (e < EE) {
    int d = dst[e];
    int pos = rs[d] + atomicAdd(&fill[d], 1);
    csr_src[pos] = src[e];
  }
}

// ---------------- per-module SGEMM, vectorized LDS, optional bf16 output ----------------
template<int K, int JT, bool TB, int RT, int KS, bool OBF>
__global__ __launch_bounds__(256) void k_gemm(const float* __restrict__ A,
    const float* __restrict__ B, const float* __restrict__ bias, void* __restrict__ Cv) {
  constexpr int jt = JT/64;
  constexpr int rtiles = NMOD/RT;
  constexpr int RPT = RT/16;
  constexpr int KCHUNK = K/KS;
  int b = blockIdx.x;
  int ks = b % KS; b /= KS;
  int ct = b % jt; b /= jt;
  int rt = b % rtiles; b /= rtiles;
  int m = b;
  int row0 = m*NMOD + rt*RT;
  int col0 = ct*64;
  __shared__ float Ast[32][RT+4];  // transposed: [kk][row]
  __shared__ float Bs[32][68];
  float acc[RPT][4] = {};
  int tid = threadIdx.x;
  int tr = (tid >> 4) * RPT;
  int tc = (tid & 15) * 4;
  const float* Bm = B + (size_t)m*K*JT;
  for (int k0 = ks*KCHUNK; k0 < (ks+1)*KCHUNK; k0 += 32) {
    constexpr int ANUM = RT*32/1024;
    #pragma unroll
    for (int i = 0; i < ANUM; ++i) {
      int it = tid + i*256;
      int rr = it >> 3, kk0 = (it & 7)*4;
      float4 t = *(const float4*)&A[(size_t)(row0+rr)*K + k0 + kk0];
      Ast[kk0+0][rr] = t.x; Ast[kk0+1][rr] = t.y; Ast[kk0+2][rr] = t.z; Ast[kk0+3][rr] = t.w;
    }
    #pragma unroll
    for (int i = 0; i < 2; ++i) {
      int it = tid + i*256;
      if (!TB) {
        int kk = it >> 4, jj0 = (it & 15)*4;
        float4 t = *(const float4*)&Bm[(size_t)(k0+kk)*JT + col0 + jj0];
        Bs[kk][jj0] = t.x; Bs[kk][jj0+1] = t.y; Bs[kk][jj0+2] = t.z; Bs[kk][jj0+3] = t.w;
      } else {
        int jj = it >> 3, kk0 = (it & 7)*4;
        float4 t = *(const float4*)&Bm[(size_t)(col0+jj)*K + k0 + kk0];
        Bs[kk0+0][jj] = t.x; Bs[kk0+1][jj] = t.y; Bs[kk0+2][jj] = t.z; Bs[kk0+3][jj] = t.w;
      }
    }
    __syncthreads();
    #pragma unroll
    for (int kk = 0; kk < 32; ++kk) {
      float4 bv = *(const float4*)&Bs[kk][tc];
      float av[RPT];
      if constexpr (RPT == 4) {
        float4 t = *(const float4*)&Ast[kk][tr];
        av[0] = t.x; av[1] = t.y; av[2] = t.z; av[3] = t.w;
      } else {
        av[0] = Ast[kk][tr]; av[1] = Ast[kk][tr+1];
      }
      #pragma unroll
      for (int i = 0; i < RPT; ++i) {
        acc[i][0] += av[i]*bv.x; acc[i][1] += av[i]*bv.y;
        acc[i][2] += av[i]*bv.z; acc[i][3] += av[i]*bv.w;
      }
    }
    __syncthreads();
  }
  float4 bb = {0,0,0,0};
  if (bias) bb = *(const float4*)&bias[m*JT + col0 + tc];
  #pragma unroll
  for (int i = 0; i < RPT; ++i) {
    float4 o = { acc[i][0]+bb.x, acc[i][1]+bb.y, acc[i][2]+bb.z, acc[i][3]+bb.w };
    size_t idx = (size_t)(row0+tr+i)*JT + col0 + tc;
    if constexpr (OBF) {
      bf16* Cp = (bf16*)Cv;
      bf16 tmp[4] = { __float2bfloat16(o.x), __float2bfloat16(o.y),
                      __float2bfloat16(o.z), __float2bfloat16(o.w) };
      *(uint2*)&Cp[idx] = *(const uint2*)tmp;
    } else {
      float* Cp = (float*)Cv + (size_t)ks*NN*JT;
      *(float4*)&Cp[idx] = o;
    }
  }
}

// ---------------- GAT scores (layer 1, H=4), bf16 h ----------------
__global__ void k_scores4(const bf16* __restrict__ h, const float* __restrict__ a_s,
                          const float* __restrict__ a_d, float* __restrict__ es,
                          float* __restrict__ ed) {
  int gw = blockIdx.x*4 + (threadIdx.x >> 6);
  int lane = threadIdx.x & 63;
  if (gw >= NN*4) return;
  int n = gw >> 2, hh = gw & 3;
  int m = n >> 10;
  float v = __bfloat162float(h[(size_t)gw*64 + lane]);
  float s = v * a_s[(m*4 + hh)*64 + lane];
  float d = v * a_d[(m*4 + hh)*64 + lane];
  #pragma unroll
  for (int off = 32; off; off >>= 1) { s += __shfl_xor(s, off); d += __shfl_xor(d, off); }
  if (lane == 0) { es[gw] = s; ed[gw] = d; }
}

// ---------------- GAT layer-2 partial combine + scores (H=1); writes bf16 h2 ----------------
__global__ void k_scores1c(const float* __restrict__ pa, const float* __restrict__ pb,
                           const float* __restrict__ a_s, const float* __restrict__ a_d,
                           bf16* __restrict__ h2, float* __restrict__ es, float* __restrict__ ed) {
  int gw = blockIdx.x*4 + (threadIdx.x >> 6);
  int lane = threadIdx.x & 63;
  if (gw >= NN) return;
  int m = gw >> 10;
  size_t idx = (size_t)gw*64 + lane;
  float v = pa[idx] + pb[idx];
  h2[idx] = __float2bfloat16(v);
  float s = v * a_s[m*64 + lane];
  float d = v * a_d[m*64 + lane];
  #pragma unroll
  for (int off = 32; off; off >>= 1) { s += __shfl_xor(s, off); d += __shfl_xor(d, off); }
  if (lane == 0) { es[gw] = s; ed[gw] = d; }
}

// ---------------- GAT layer-1 aggregation: one wave per node, all 4 heads ----------------
// h layout [n][4][64] bf16 (256/node); lane l covers channels 4l..4l+3; head = l>>4.
__global__ __launch_bounds__(256) void k_agg4(const bf16* __restrict__ h,
    const float* __restrict__ es, const float* __restrict__ ed, const int* __restrict__ rs,
    const int* __restrict__ csr_src, const float* __restrict__ bias, float* __restrict__ out) {
  int wid = __builtin_amdgcn_readfirstlane(threadIdx.x >> 6);
  int n = blockIdx.x*4 + wid;
  int lane = threadIdx.x & 63;
  int hh = lane >> 4;
  int m = n >> 10;
  const unsigned short* hp = (const unsigned short*)h;
  float edv = ed[n*4 + hh];
  float p0 = __expf(lrelu(es[n*4 + hh] + edv));   // self-loop
  float den = p0;
  ushort4 v0 = *(const ushort4*)&hp[(size_t)n*256 + lane*4];
  float a0 = p0*bfu(v0.x), a1 = p0*bfu(v0.y), a2 = p0*bfu(v0.z), a3 = p0*bfu(v0.w);
  int beg = rs[n], end = rs[n+1];
  int i = beg;
  for (; i + 4 <= end; i += 4) {
    int s0 = csr_src[i], s1 = csr_src[i+1], s2 = csr_src[i+2], s3 = csr_src[i+3];
    ushort4 w0 = *(const ushort4*)&hp[(size_t)s0*256 + lane*4];
    ushort4 w1 = *(const ushort4*)&hp[(size_t)s1*256 + lane*4];
    ushort4 w2 = *(const ushort4*)&hp[(size_t)s2*256 + lane*4];
    ushort4 w3 = *(const ushort4*)&hp[(size_t)s3*256 + lane*4];
    float e0 = es[s0*4 + hh], e1 = es[s1*4 + hh], e2 = es[s2*4 + hh], e3 = es[s3*4 + hh];
    float q0 = __expf(lrelu(e0 + edv));
    float q1 = __expf(lrelu(e1 + edv));
    float q2 = __expf(lrelu(e2 + edv));
    float q3 = __expf(lrelu(e3 + edv));
    den += (q0 + q1) + (q2 + q3);
    a0 += q0*bfu(w0.x); a1 += q0*bfu(w0.y); a2 += q0*bfu(w0.z); a3 += q0*bfu(w0.w);
    a0 += q1*bfu(w1.x); a1 += q1*bfu(w1.y); a2 += q1*bfu(w1.z); a3 += q1*bfu(w1.w);
    a0 += q2*bfu(w2.x); a1 += q2*bfu(w2.y); a2 += q2*bfu(w2.z); a3 += q2*bfu(w2.w);
    a0 += q3*bfu(w3.x); a1 += q3*bfu(w3.y); a2 += q3*bfu(w3.z); a3 += q3*bfu(w3.w);
  }
  for (; i < end; ++i) {
    int s = csr_src[i];
    ushort4 w = *(const ushort4*)&hp[(size_t)s*256 + lane*4];
    float q = __expf(lrelu(es[s*4 + hh] + edv));
    den += q;
    a0 += q*bfu(w.x); a1 += q*bfu(w.y); a2 += q*bfu(w.z); a3 += q*bfu(w.w);
  }
  float inv = 1.f/den;
  float4 bb = *(const float4*)&bias[m*256 + lane*4];
  float4 o = { fmaxf(a0*inv + bb.x, 0.f), fmaxf(a1*inv + bb.y, 0.f),
               fmaxf(a2*inv + bb.z, 0.f), fmaxf(a3*inv + bb.w, 0.f) };
  *(float4*)&out[(size_t)n*256 + lane*4] = o;
}

// ---------------- GAT layer-2 aggregation (H=1, per-(node) wave) ----------------
__global__ __launch_bounds__(256) void k_agg1(const bf16* __restrict__ h,
    const float* __restrict__ es, const float* __restrict__ ed, const int* __restrict__ rs,
    const int* __restrict__ csr_src, const float* __restrict__ bias, float* __restrict__ out) {
  int wid = __builtin_amdgcn_readfirstlane(threadIdx.x >> 6);
  int n = blockIdx.x*4 + wid;
  int lane = threadIdx.x & 63;
  int m = n >> 10;
  float edv = ed[n];
  float p0 = __expf(lrelu(es[n] + edv));
  float den = p0;
  float acc = p0 * __bfloat162float(h[(size_t)n*64 + lane]);
  int beg = rs[n], end = rs[n+1];
  int i = beg;
  for (; i + 4 <= end; i += 4) {
    int s0 = csr_src[i], s1 = csr_src[i+1], s2 = csr_src[i+2], s3 = csr_src[i+3];
    float e0 = es[s0], e1 = es[s1], e2 = es[s2], e3 = es[s3];
    float v0 = __bfloat162float(h[(size_t)s0*64 + lane]);
    float v1 = __bfloat162float(h[(size_t)s1*64 + lane]);
    float v2 = __bfloat162float(h[(size_t)s2*64 + lane]);
    float v3 = __bfloat162float(h[(size_t)s3*64 + lane]);
    float q0 = __expf(lrelu(e0 + edv));
    float q1 = __expf(lrelu(e1 + edv));
    float q2 = __expf(lrelu(e2 + edv));
    float q3 = __expf(lrelu(e3 + edv));
    den += (q0 + q1) + (q2 + q3);
    acc += q0*v0; acc += q1*v1; acc += q2*v2; acc += q3*v3;
  }
  for (; i < end; ++i) {
    int s = csr_src[i];
    float q = __expf(lrelu(es[s] + edv));
    den += q;
    acc += q * __bfloat162float(h[(size_t)s*64 + lane]);
  }
  float v = acc/den + bias[m*64 + lane];
  out[(size_t)n*64 + lane] = fmaxf(v, 0.f);
}

// ---------------- self-attention: lane=query, wave-uniform K/V via s_load ----------------
// grid = MODS*16*4*KC2; block 256 = 4 waves = 4 key sub-chunks of 64.
__global__ __launch_bounds__(256) void k_attn(const float* __restrict__ qkv,
    float* __restrict__ pd, float* __restrict__ pacc) {
  int b = blockIdx.x;
  int kcg = b & (KC2-1); b /= KC2;
  int h = b & 3; b >>= 2;
  int qt = b & 15; int m = b >> 4;
  int lane = threadIdx.x & 63;
  int wu = __builtin_amdgcn_readfirstlane(threadIdx.x >> 6);
  int n = m*NMOD + qt*64 + lane;
  float2 q2[8];
  const float* qrow = qkv + (size_t)n*192 + h*16;
  #pragma unroll
  for (int c = 0; c < 8; ++c) {
    float2 t = *(const float2*)(qrow + 2*c);
    q2[c] = make_float2(t.x*0.25f, t.y*0.25f);
  }
  const float* kb = qkv + (size_t)(m*NMOD + kcg*256 + wu*64)*192 + 64 + h*16;
  float den = 0.f;
  float2 acc2[8] = {};
  #pragma unroll 2
  for (int j = 0; j < 64; ++j) {
    const float2* kr2 = (const float2*)(kb + (size_t)j*192);
    float2 d0 = {0,0}, d1 = {0,0};
    #pragma unroll
    for (int c = 0; c < 8; c += 2) { d0 = f2fma(q2[c], kr2[c], d0); d1 = f2fma(q2[c+1], kr2[c+1], d1); }
    float p = __expf((d0.x + d0.y) + (d1.x + d1.y));
    den += p;
    const float2* vr2 = (const float2*)(kb + (size_t)j*192 + 64);
    float2 pp = {p, p};
    #pragma unroll
    for (int c = 0; c < 8; ++c) acc2[c] = f2fma(pp, vr2[c], acc2[c]);
  }
  __shared__ float red[4][64][17];
  #pragma unroll
  for (int c = 0; c < 8; ++c) { red[wu][lane][2*c] = acc2[c].x; red[wu][lane][2*c+1] = acc2[c].y; }
  red[wu][lane][16] = den;
  __syncthreads();
  if (wu == 0) {
    size_t o = ((size_t)n*4 + h)*KC2 + kcg;
    pd[o] = red[0][lane][16] + red[1][lane][16] + red[2][lane][16] + red[3][lane][16];
    #pragma unroll
    for (int c = 0; c < 16; ++c)
      pacc[o*16 + c] = red[0][lane][c] + red[1][lane][c] + red[2][lane][c] + red[3][lane][c];
  }
}

__global__ void k_attn_combine(const float* __restrict__ pd, const float* __restrict__ pacc,
                               float* __restrict__ attn) {
  int t = blockIdx.x*256 + threadIdx.x;   // (n, h)
  if (t >= NN*4) return;
  float den = 0.f;
  #pragma unroll
  for (int kc = 0; kc < KC2; ++kc) den += pd[(size_t)t*KC2 + kc];
  float inv = 1.f/den;
  int n = t >> 2, h = t & 3;
  #pragma unroll
  for (int c = 0; c < 16; ++c) {
    float s = 0.f;
    #pragma unroll
    for (int kc = 0; kc < KC2; ++kc) s += pacc[((size_t)t*KC2 + kc)*16 + c];
    attn[(size_t)n*64 + h*16 + c] = s*inv;
  }
}

// ---------------- node-mean + folded output projection -> reps ----------------
__global__ void k_reps(const float* __restrict__ attn, const float* __restrict__ out_w,
                       const float* __restrict__ out_b, float* __restrict__ reps,
                       float* __restrict__ dout) {
  int m = blockIdx.x;
  __shared__ float part[4][64];
  __shared__ float abar[64];
  int c = threadIdx.x & 63, pp = threadIdx.x >> 6;
  float s = 0.f;
  const float* base = attn + (size_t)m*NMOD*64;
  for (int i = pp*256; i < pp*256 + 256; ++i) s += base[(size_t)i*64 + c];
  part[pp][c] = s;
  __syncthreads();
  if (pp == 0) abar[c] = (part[0][c]+part[1][c]+part[2][c]+part[3][c]) * (1.f/NMOD);
  __syncthreads();
  if (threadIdx.x < 64) {
    int j = threadIdx.x;
    float r = out_b[m*64 + j];
    const float* wr = out_w + (size_t)m*64*64 + (size_t)j*64;
    #pragma unroll
    for (int k = 0; k < 64; ++k) r += abar[k]*wr[k];
    reps[m*64 + j] = r;
    dout[2 + m*64 + j] = r;     // Output 1
  }
}

// ---------------- cross-attention + fusion + classifier (single block, lane-parallel) ----------------
__global__ __launch_bounds__(256) void k_final(const float* __restrict__ reps,
    const float* __restrict__ ca_in_w, const float* __restrict__ ca_in_b,
    const float* __restrict__ ca_out_w, const float* __restrict__ ca_out_b,
    const float* __restrict__ fusion_w, const float* __restrict__ fc_w,
    const float* __restrict__ fc_b, const float* __restrict__ c1_w,
    const float* __restrict__ c1_b, const float* __restrict__ c2_w,
    const float* __restrict__ c2_b, float* __restrict__ dout) {
  __shared__ float R[7][64];
  __shared__ float QKV[7][192];
  __shared__ float SC[4][7][8];
  __shared__ float AL[4][7][8];
  __shared__ float O[7][64];
  __shared__ float CR[7][64];
  __shared__ float W[8];
  __shared__ float part[4][64];
  __shared__ float FU[64];
  __shared__ float HM[32];
  int tid = threadIdx.x, lane = tid & 63;
  for (int i = tid; i < 448; i += 256) R[i>>6][i&63] = reps[i];
  __syncthreads();
  // Phase A: QKV = R @ ca_in_w^T + b. 1344 outputs, 4 threads per 64-dot.
  {
    int sub = tid & 3, tt0 = tid >> 2;
    #pragma unroll 3
    for (int it = 0; it < 21; ++it) {
      int t = tt0 + it*64;
      int r = t/192, j = t - r*192;
      const float4* wr = (const float4*)&ca_in_w[j*64 + sub*16];
      const float4* rr = (const float4*)&R[r][sub*16];
      float s = 0.f;
      #pragma unroll
      for (int c = 0; c < 4; ++c) {
        float4 a = rr[c], w4 = wr[c];
        s += a.x*w4.x + a.y*w4.y + a.z*w4.z + a.w*w4.w;
      }
      s += __shfl_xor(s, 1); s += __shfl_xor(s, 2);
      if (sub == 0) QKV[r][j] = s + ca_in_b[j];
    }
    if (tid == 252) {  // fusion softmax (needed only in phase F)
      float p[7]; float den = 0.f;
      #pragma unroll
      for (int i = 0; i < 7; ++i) { p[i] = __expf(fusion_w[i]); den += p[i]; }
      float inv = 1.f/den;
      #pragma unroll
      for (int i = 0; i < 7; ++i) W[i] = p[i]*inv;
    }
  }
  __syncthreads();
  // Phase B: 196 (h,q,k) score exps
  if (tid < 196) {
    int hh = tid/49, rem = tid - hh*49, qi = rem/7, ki = rem - qi*7;
    float s = 0.f;
    #pragma unroll
    for (int c = 0; c < 16; ++c) s += QKV[qi][hh*16 + c]*QKV[ki][64 + hh*16 + c];
    SC[hh][qi][ki] = __expf(s*0.25f);
  }
  __syncthreads();
  if (tid < 28) {
    int hh = tid/7, qi = tid - hh*7;
    float den = 0.f;
    #pragma unroll
    for (int k = 0; k < 7; ++k) den += SC[hh][qi][k];
    float inv = 1.f/den;
    #pragma unroll
    for (int k = 0; k < 7; ++k) AL[hh][qi][k] = SC[hh][qi][k]*inv;
  }
  __syncthreads();
  // Phase C: O = alpha @ V
  for (int i = tid; i < 448; i += 256) {
    int qi = i >> 6, j = i & 63, hh = j >> 4;
    float s = 0.f;
    #pragma unroll
    for (int k = 0; k < 7; ++k) s += AL[hh][qi][k]*QKV[k][128 + j];
    O[qi][j] = s;
  }
  __syncthreads();
  // Phase D: CR = O @ ca_out_w^T + b. 448 outputs × 4 threads = 7 iters.
  {
    int sub = tid & 3, tt0 = tid >> 2;
    #pragma unroll
    for (int it = 0; it < 7; ++it) {
      int t = tt0 + it*64;
      int qi = t >> 6, j = t & 63;
      const float4* wr = (const float4*)&ca_out_w[j*64 + sub*16];
      const float4* orow = (const float4*)&O[qi][sub*16];
      float s = 0.f;
      #pragma unroll
      for (int c = 0; c < 4; ++c) {
        float4 a = orow[c], w4 = wr[c];
        s += a.x*w4.x + a.y*w4.y + a.z*w4.z + a.w*w4.w;
      }
      s += __shfl_xor(s, 1); s += __shfl_xor(s, 2);
      if (sub == 0) CR[qi][j] = s + ca_out_b[j];
    }
  }
  __syncthreads();
  // Phase F: FU[j] = fc_b[j] + sum_i CR[i]*W[i/64]*fc_w[i][j], split over 4 waves
  {
    int w = tid >> 6;
    float s = 0.f;
    #pragma unroll 4
    for (int i = w*112; i < w*112 + 112; ++i)
      s += CR[i>>6][i&63]*W[i>>6]*fc_w[(size_t)i*64 + lane];
    part[w][lane] = s;
  }
  __syncthreads();
  if (tid < 64) FU[tid] = part[0][tid] + part[1][tid] + part[2][tid] + part[3][tid] + fc_b[tid];
  __syncthreads();
  // Phase G: HM = relu(FU @ c1_w + b). 32 outputs × 4 threads.
  if (tid < 128) {
    int sub = tid & 3, j = tid >> 2;
    float s = 0.f;
    #pragma unroll
    for (int c = 0; c < 16; ++c) { int k = sub*16 + c; s += FU[k]*c1_w[k*32 + j]; }
    s += __shfl_xor(s, 1); s += __shfl_xor(s, 2);
    if (sub == 0) HM[j] = fmaxf(s + c1_b[j], 0.f);
  }
  __syncthreads();
  if (tid < 2) {
    float s = c2_b[tid];
    #pragma unroll
    for (int k = 0; k < 32; ++k) s += HM[k]*c2_w[k*2 + tid];
    dout[tid] = s;              // Output 0
  }
}

extern "C" void kernel_launch(void* const* d_in, const int* in_sizes, int n_in,
                              void* d_out, int out_size, void* d_ws, size_t ws_size,
                              hipStream_t stream) {
  (void)in_sizes; (void)n_in; (void)out_size; (void)ws_size;
  const float* x       = (const float*)d_in[0];
  const int*   ei      = (const int*)d_in[1];
  const float* g1_w    = (const float*)d_in[3];
  const float* g1_as   = (const float*)d_in[4];
  const float* g1_ad   = (const float*)d_in[5];
  const float* g1_b    = (const float*)d_in[6];
  const float* g2_w    = (const float*)d_in[7];
  const float* g2_as   = (const float*)d_in[8];
  const float* g2_ad   = (const float*)d_in[9];
  const float* g2_b    = (const float*)d_in[10];
  const float* sa_in_w = (const float*)d_in[11];
  const float* sa_in_b = (const float*)d_in[12];
  const float* sa_out_w= (const float*)d_in[13];
  const float* sa_out_b= (const float*)d_in[14];
  const float* ca_in_w = (const float*)d_in[15];
  const float* ca_in_b = (const float*)d_in[16];
  const float* ca_out_w= (const float*)d_in[17];
  const float* ca_out_b= (const float*)d_in[18];
  const float* fusion_w= (const float*)d_in[19];
  const float* fc_w    = (const float*)d_in[20];
  const float* fc_b    = (const float*)d_in[21];
  const float* c1_w    = (const float*)d_in[22];
  const float* c1_b    = (const float*)d_in[23];
  const float* c2_w    = (const float*)d_in[24];
  const float* c2_b    = (const float*)d_in[25];
  float* dout = (float*)d_out;

  const int* src = ei;        // edge_index[0]
  const int* dst = ei + EE;   // edge_index[1]

  // ---- workspace carve (aliasing by lifetime) ----
  char* p = (char*)d_ws;
  int* cnt     = (int*)p; p += (size_t)NN*sizeof(int);
  int* fill    = (int*)p; p += (size_t)NN*sizeof(int);
  int* rs      = (int*)p; p += (size_t)(NN+4)*sizeof(int);
  int* csr_src = (int*)p; p += (size_t)EE*sizeof(int);
  p = (char*)(((uintptr_t)p + 255) & ~(uintptr_t)255);
  float* h1f  = (float*)p; p += (size_t)NN*256*4;   // bf16 h1; later h2 partials; later qkv (f32)
  float* es1  = (float*)p; p += (size_t)NN*4*4;
  float* ed1  = (float*)p; p += (size_t)NN*4*4;
  float* gat1 = (float*)p; p += (size_t)NN*256*4;   // later: pacc
  float* h2f  = (float*)p; p += (size_t)NN*64*4;    // bf16 h2; later pd
  float* es2  = (float*)p; p += (size_t)NN*4;
  float* ed2  = (float*)p; p += (size_t)NN*4;
  float* z    = (float*)p; p += (size_t)NN*64*4;
  float* attn = (float*)p; p += (size_t)NN*64*4;
  float* reps = (float*)p; p += (size_t)MODS*64*4;
  bf16* h1    = (bf16*)h1f;
  bf16* h2    = (bf16*)h2f;
  float* h2a  = h1f;                 // K-split partials; h1 dead after k_agg4
  float* h2b  = h1f + (size_t)NN*64;
  float* qkv  = h1f;                 // h2a/h2b dead after k_scores1c
  float* pacc = gat1;                // NN*256 floats; gat1 dead after layer-2 gemm
  float* pd   = h2f;                 // NN*16 floats; h2 dead after k_agg1

  hipMemsetAsync(cnt, 0, 2*(size_t)NN*sizeof(int), stream);   // cnt + fill
  k_count<<<(EE+255)/256, 256, 0, stream>>>(dst, cnt);
  k_scan<<<1, 1024, 0, stream>>>(cnt, rs);
  k_fill<<<(EE+255)/256, 256, 0, stream>>>(src, dst, rs, fill, csr_src);

  // GAT layer 1 (h1 in bf16)
  k_gemm<128,256,false,64,1,true><<<MODS*16*4, 256, 0, stream>>>(x, g1_w, nullptr, h1);
  k_scores4<<<NN, 256, 0, stream>>>(h1, g1_as, g1_ad, es1, ed1);
  k_agg4<<<NN/4, 256, 0, stream>>>(h1, es1, ed1, rs, csr_src, g1_b, gat1);

  // GAT layer 2 (K-split 2; combine + scores fused; h2 in bf16)
  k_gemm<256,64,false,32,2,false><<<MODS*32*2, 256, 0, stream>>>(gat1, g2_w, nullptr, h2a);
  k_scores1c<<<NN/4, 256, 0, stream>>>(h2a, h2b, g2_as, g2_ad, h2, es2, ed2);
  k_agg1<<<NN/4, 256, 0, stream>>>(h2, es2, ed2, rs, csr_src, g2_b, z);

  // self-attention
  k_gemm<64,192,true,64,1,false><<<MODS*16*3, 256, 0, stream>>>(z, sa_in_w, sa_in_b, qkv);
  k_attn<<<MODS*16*4*KC2, 256, 0, stream>>>(qkv, pd, pacc);
  k_attn_combine<<<(NN*4+255)/256, 256, 0, stream>>>(pd, pacc, attn);

  // reps (Output 1), then head (Output 0)
  k_reps<<<MODS, 256, 0, stream>>>(attn, sa_out_w, sa_out_b, reps, dout);
  k_final<<<1, 256, 0, stream>>>(reps, ca_in_w, ca_in_b, ca_out_w, ca_out_b,
                                 fusion_w, fc_w, fc_b, c1_w, c1_b, c2_w, c2_b, dout);
}

// Round 5
// 171.573 us; speedup vs baseline: 2.0428x; 1.0205x over previous
//
#include <hip/hip_runtime.h>
#include <hip/hip_bf16.h>
#include <stdint.h>

#define MODS 7
#define NMOD 1024
#define EMOD 32768
#define NN (MODS*NMOD)   // 7168 nodes
#define EE (MODS*EMOD)   // 229376 edges
#define KC2 4            // block-level key chunks for self-attention

typedef __hip_bfloat16 bf16;

static __device__ __forceinline__ float lrelu(float x){ return x > 0.f ? x : 0.2f*x; }
static __device__ __forceinline__ float bfu(unsigned short u){ return __uint_as_float(((unsigned)u) << 16); }
static __device__ __forceinline__ float2 f2fma(float2 a, float2 b, float2 c){
  return make_float2(fmaf(a.x,b.x,c.x), fmaf(a.y,b.y,c.y));
}

// ---------------- CSR build ----------------
__global__ void k_zero(int* __restrict__ cnt) {
  int i = blockIdx.x*256 + threadIdx.x;   // grid covers NN/4 int4s
  ((int4*)cnt)[i] = make_int4(0,0,0,0);
}

__global__ void k_count(const int* __restrict__ dst, int* __restrict__ cnt) {
  int e = blockIdx.x*256 + threadIdx.x;
  if (e < EE) atomicAdd(&cnt[dst[e]], 1);
}

__global__ void k_scan(const int* __restrict__ cnt, int* __restrict__ rs, int* __restrict__ rs2) {
  __shared__ int wsum[16];
  __shared__ int carry;
  int tid = threadIdx.x, lane = tid & 63, wid = tid >> 6;
  if (tid == 0) carry = 0;
  __syncthreads();
  for (int base = 0; base < NN; base += 1024) {
    int i = base + tid;
    int v = (i < NN) ? cnt[i] : 0;
    int x = v;
    #pragma unroll
    for (int off = 1; off < 64; off <<= 1) { int t = __shfl_up(x, off); if (lane >= off) x += t; }
    if (lane == 63) wsum[wid] = x;
    __syncthreads();
    if (wid == 0 && lane < 16) {
      int y = wsum[lane];
      #pragma unroll
      for (int off = 1; off < 16; off <<= 1) { int t = __shfl_up(y, off, 16); if (lane >= off) y += t; }
      wsum[lane] = y;
    }
    __syncthreads();
    int woff = wid ? wsum[wid-1] : 0;
    int c = carry;
    if (i < NN) { int ex = x - v + woff + c; rs[i] = ex; rs2[i] = ex; }   // exclusive
    __syncthreads();
    if (tid == 0) carry += wsum[15];
    __syncthreads();
  }
  if (threadIdx.x == 0) rs[NN] = carry;
}

// rs2 doubles as the fill cursor (starts at rs[d], ends at rs[d+1]; rebuilt every call)
__global__ void k_fill(const int* __restrict__ src, const int* __restrict__ dst,
                       int* __restrict__ rs2, int* __restrict__ csr_src) {
  int e = blockIdx.x*256 + threadIdx.x;
  if (e < EE) {
    int pos = atomicAdd(&rs2[dst[e]], 1);
    csr_src[pos] = src[e];
  }
}

// ---------------- per-module SGEMM; optional bf16 out; optional fused GAT-1 scores ----------------
// SC4: JT==256, ct==head; es/ed computed from fp32 acc via 16-lane reduce.
template<int K, int JT, bool TB, int RT, int KS, bool OBF, bool SC4>
__global__ __launch_bounds__(256) void k_gemm(const float* __restrict__ A,
    const float* __restrict__ B, const float* __restrict__ bias, void* __restrict__ Cv,
    const float* __restrict__ a_s, const float* __restrict__ a_d,
    float* __restrict__ es, float* __restrict__ ed) {
  constexpr int jt = JT/64;
  constexpr int rtiles = NMOD/RT;
  constexpr int RPT = RT/16;
  constexpr int KCHUNK = K/KS;
  int b = blockIdx.x;
  int ks = b % KS; b /= KS;
  int ct = b % jt; b /= jt;
  int rt = b % rtiles; b /= rtiles;
  int m = b;
  int row0 = m*NMOD + rt*RT;
  int col0 = ct*64;
  __shared__ float Ast[32][RT+4];  // transposed: [kk][row]
  __shared__ float Bs[32][68];
  float acc[RPT][4] = {};
  int tid = threadIdx.x;
  int tr = (tid >> 4) * RPT;
  int tc = (tid & 15) * 4;
  const float* Bm = B + (size_t)m*K*JT;
  for (int k0 = ks*KCHUNK; k0 < (ks+1)*KCHUNK; k0 += 32) {
    constexpr int ANUM = RT*32/1024;
    #pragma unroll
    for (int i = 0; i < ANUM; ++i) {
      int it = tid + i*256;
      int rr = it >> 3, kk0 = (it & 7)*4;
      float4 t = *(const float4*)&A[(size_t)(row0+rr)*K + k0 + kk0];
      Ast[kk0+0][rr] = t.x; Ast[kk0+1][rr] = t.y; Ast[kk0+2][rr] = t.z; Ast[kk0+3][rr] = t.w;
    }
    #pragma unroll
    for (int i = 0; i < 2; ++i) {
      int it = tid + i*256;
      if (!TB) {
        int kk = it >> 4, jj0 = (it & 15)*4;
        float4 t = *(const float4*)&Bm[(size_t)(k0+kk)*JT + col0 + jj0];
        Bs[kk][jj0] = t.x; Bs[kk][jj0+1] = t.y; Bs[kk][jj0+2] = t.z; Bs[kk][jj0+3] = t.w;
      } else {
        int jj = it >> 3, kk0 = (it & 7)*4;
        float4 t = *(const float4*)&Bm[(size_t)(col0+jj)*K + k0 + kk0];
        Bs[kk0+0][jj] = t.x; Bs[kk0+1][jj] = t.y; Bs[kk0+2][jj] = t.z; Bs[kk0+3][jj] = t.w;
      }
    }
    __syncthreads();
    #pragma unroll
    for (int kk = 0; kk < 32; ++kk) {
      float4 bv = *(const float4*)&Bs[kk][tc];
      float av[RPT];
      if constexpr (RPT == 4) {
        float4 t = *(const float4*)&Ast[kk][tr];
        av[0] = t.x; av[1] = t.y; av[2] = t.z; av[3] = t.w;
      } else {
        av[0] = Ast[kk][tr]; av[1] = Ast[kk][tr+1];
      }
      #pragma unroll
      for (int i = 0; i < RPT; ++i) {
        acc[i][0] += av[i]*bv.x; acc[i][1] += av[i]*bv.y;
        acc[i][2] += av[i]*bv.z; acc[i][3] += av[i]*bv.w;
      }
    }
    __syncthreads();
  }
  float4 bb = {0,0,0,0};
  if (bias) bb = *(const float4*)&bias[m*JT + col0 + tc];
  #pragma unroll
  for (int i = 0; i < RPT; ++i) {
    float4 o = { acc[i][0]+bb.x, acc[i][1]+bb.y, acc[i][2]+bb.z, acc[i][3]+bb.w };
    size_t idx = (size_t)(row0+tr+i)*JT + col0 + tc;
    if constexpr (OBF) {
      bf16* Cp = (bf16*)Cv;
      bf16 tmp[4] = { __float2bfloat16(o.x), __float2bfloat16(o.y),
                      __float2bfloat16(o.z), __float2bfloat16(o.w) };
      *(uint2*)&Cp[idx] = *(const uint2*)tmp;
    } else {
      float* Cp = (float*)Cv + (size_t)ks*NN*JT;
      *(float4*)&Cp[idx] = o;
    }
  }
  if constexpr (SC4) {
    // fused GAT layer-1 scores: hh = ct; this block owns rows row0..row0+RT-1 of head hh fully.
    int hh = ct;
    float4 as4 = *(const float4*)&a_s[(m*4 + hh)*64 + tc];
    float4 ad4 = *(const float4*)&a_d[(m*4 + hh)*64 + tc];
    #pragma unroll
    for (int i = 0; i < RPT; ++i) {
      float s = acc[i][0]*as4.x + acc[i][1]*as4.y + acc[i][2]*as4.z + acc[i][3]*as4.w;
      float d = acc[i][0]*ad4.x + acc[i][1]*ad4.y + acc[i][2]*ad4.z + acc[i][3]*ad4.w;
      #pragma unroll
      for (int off = 1; off < 16; off <<= 1) { s += __shfl_xor(s, off); d += __shfl_xor(d, off); }
      if ((tid & 15) == 0) {
        es[(row0+tr+i)*4 + hh] = s;
        ed[(row0+tr+i)*4 + hh] = d;
      }
    }
  }
}

// ---------------- GAT layer-2 partial combine + scores (H=1); writes bf16 h2 ----------------
__global__ void k_scores1c(const float* __restrict__ pa, const float* __restrict__ pb,
                           const float* __restrict__ a_s, const float* __restrict__ a_d,
                           bf16* __restrict__ h2, float* __restrict__ es, float* __restrict__ ed) {
  int gw = blockIdx.x*4 + (threadIdx.x >> 6);
  int lane = threadIdx.x & 63;
  if (gw >= NN) return;
  int m = gw >> 10;
  size_t idx = (size_t)gw*64 + lane;
  float v = pa[idx] + pb[idx];
  h2[idx] = __float2bfloat16(v);
  float s = v * a_s[m*64 + lane];
  float d = v * a_d[m*64 + lane];
  #pragma unroll
  for (int off = 32; off; off >>= 1) { s += __shfl_xor(s, off); d += __shfl_xor(d, off); }
  if (lane == 0) { es[gw] = s; ed[gw] = d; }
}

// ---------------- GAT layer-1 aggregation: one wave per node, all 4 heads ----------------
__global__ __launch_bounds__(256) void k_agg4(const bf16* __restrict__ h,
    const float* __restrict__ es, const float* __restrict__ ed, const int* __restrict__ rs,
    const int* __restrict__ csr_src, const float* __restrict__ bias, float* __restrict__ out) {
  int wid = __builtin_amdgcn_readfirstlane(threadIdx.x >> 6);
  int n = blockIdx.x*4 + wid;
  int lane = threadIdx.x & 63;
  int hh = lane >> 4;
  int m = n >> 10;
  const unsigned short* hp = (const unsigned short*)h;
  float edv = ed[n*4 + hh];
  float p0 = __expf(lrelu(es[n*4 + hh] + edv));   // self-loop
  float den = p0;
  ushort4 v0 = *(const ushort4*)&hp[(size_t)n*256 + lane*4];
  float a0 = p0*bfu(v0.x), a1 = p0*bfu(v0.y), a2 = p0*bfu(v0.z), a3 = p0*bfu(v0.w);
  int beg = rs[n], end = rs[n+1];
  int i = beg;
  for (; i + 4 <= end; i += 4) {
    int s0 = csr_src[i], s1 = csr_src[i+1], s2 = csr_src[i+2], s3 = csr_src[i+3];
    ushort4 w0 = *(const ushort4*)&hp[(size_t)s0*256 + lane*4];
    ushort4 w1 = *(const ushort4*)&hp[(size_t)s1*256 + lane*4];
    ushort4 w2 = *(const ushort4*)&hp[(size_t)s2*256 + lane*4];
    ushort4 w3 = *(const ushort4*)&hp[(size_t)s3*256 + lane*4];
    float e0 = es[s0*4 + hh], e1 = es[s1*4 + hh], e2 = es[s2*4 + hh], e3 = es[s3*4 + hh];
    float q0 = __expf(lrelu(e0 + edv));
    float q1 = __expf(lrelu(e1 + edv));
    float q2 = __expf(lrelu(e2 + edv));
    float q3 = __expf(lrelu(e3 + edv));
    den += (q0 + q1) + (q2 + q3);
    a0 += q0*bfu(w0.x); a1 += q0*bfu(w0.y); a2 += q0*bfu(w0.z); a3 += q0*bfu(w0.w);
    a0 += q1*bfu(w1.x); a1 += q1*bfu(w1.y); a2 += q1*bfu(w1.z); a3 += q1*bfu(w1.w);
    a0 += q2*bfu(w2.x); a1 += q2*bfu(w2.y); a2 += q2*bfu(w2.z); a3 += q2*bfu(w2.w);
    a0 += q3*bfu(w3.x); a1 += q3*bfu(w3.y); a2 += q3*bfu(w3.z); a3 += q3*bfu(w3.w);
  }
  for (; i < end; ++i) {
    int s = csr_src[i];
    ushort4 w = *(const ushort4*)&hp[(size_t)s*256 + lane*4];
    float q = __expf(lrelu(es[s*4 + hh] + edv));
    den += q;
    a0 += q*bfu(w.x); a1 += q*bfu(w.y); a2 += q*bfu(w.z); a3 += q*bfu(w.w);
  }
  float inv = 1.f/den;
  float4 bb = *(const float4*)&bias[m*256 + lane*4];
  float4 o = { fmaxf(a0*inv + bb.x, 0.f), fmaxf(a1*inv + bb.y, 0.f),
               fmaxf(a2*inv + bb.z, 0.f), fmaxf(a3*inv + bb.w, 0.f) };
  *(float4*)&out[(size_t)n*256 + lane*4] = o;
}

// ---------------- GAT layer-2 aggregation (H=1, per-node wave) ----------------
__global__ __launch_bounds__(256) void k_agg1(const bf16* __restrict__ h,
    const float* __restrict__ es, const float* __restrict__ ed, const int* __restrict__ rs,
    const int* __restrict__ csr_src, const float* __restrict__ bias, float* __restrict__ out) {
  int wid = __builtin_amdgcn_readfirstlane(threadIdx.x >> 6);
  int n = blockIdx.x*4 + wid;
  int lane = threadIdx.x & 63;
  int m = n >> 10;
  float edv = ed[n];
  float p0 = __expf(lrelu(es[n] + edv));
  float den = p0;
  float acc = p0 * __bfloat162float(h[(size_t)n*64 + lane]);
  int beg = rs[n], end = rs[n+1];
  int i = beg;
  for (; i + 4 <= end; i += 4) {
    int s0 = csr_src[i], s1 = csr_src[i+1], s2 = csr_src[i+2], s3 = csr_src[i+3];
    float e0 = es[s0], e1 = es[s1], e2 = es[s2], e3 = es[s3];
    float v0 = __bfloat162float(h[(size_t)s0*64 + lane]);
    float v1 = __bfloat162float(h[(size_t)s1*64 + lane]);
    float v2 = __bfloat162float(h[(size_t)s2*64 + lane]);
    float v3 = __bfloat162float(h[(size_t)s3*64 + lane]);
    float q0 = __expf(lrelu(e0 + edv));
    float q1 = __expf(lrelu(e1 + edv));
    float q2 = __expf(lrelu(e2 + edv));
    float q3 = __expf(lrelu(e3 + edv));
    den += (q0 + q1) + (q2 + q3);
    acc += q0*v0; acc += q1*v1; acc += q2*v2; acc += q3*v3;
  }
  for (; i < end; ++i) {
    int s = csr_src[i];
    float q = __expf(lrelu(es[s] + edv));
    den += q;
    acc += q * __bfloat162float(h[(size_t)s*64 + lane]);
  }
  float v = acc/den + bias[m*64 + lane];
  out[(size_t)n*64 + lane] = fmaxf(v, 0.f);
}

// ---------------- self-attention: lane=query, wave-uniform K/V via s_load ----------------
__global__ __launch_bounds__(256) void k_attn(const float* __restrict__ qkv,
    float* __restrict__ pd, float* __restrict__ pacc) {
  int b = blockIdx.x;
  int kcg = b & (KC2-1); b /= KC2;
  int h = b & 3; b >>= 2;
  int qt = b & 15; int m = b >> 4;
  int lane = threadIdx.x & 63;
  int wu = __builtin_amdgcn_readfirstlane(threadIdx.x >> 6);
  int n = m*NMOD + qt*64 + lane;
  float2 q2[8];
  const float* qrow = qkv + (size_t)n*192 + h*16;
  #pragma unroll
  for (int c = 0; c < 8; ++c) {
    float2 t = *(const float2*)(qrow + 2*c);
    q2[c] = make_float2(t.x*0.25f, t.y*0.25f);
  }
  const float* kb = qkv + (size_t)(m*NMOD + kcg*256 + wu*64)*192 + 64 + h*16;
  float den = 0.f;
  float2 acc2[8] = {};
  #pragma unroll 2
  for (int j = 0; j < 64; ++j) {
    const float2* kr2 = (const float2*)(kb + (size_t)j*192);
    float2 d0 = {0,0}, d1 = {0,0};
    #pragma unroll
    for (int c = 0; c < 8; c += 2) { d0 = f2fma(q2[c], kr2[c], d0); d1 = f2fma(q2[c+1], kr2[c+1], d1); }
    float p = __expf((d0.x + d0.y) + (d1.x + d1.y));
    den += p;
    const float2* vr2 = (const float2*)(kb + (size_t)j*192 + 64);
    float2 pp = {p, p};
    #pragma unroll
    for (int c = 0; c < 8; ++c) acc2[c] = f2fma(pp, vr2[c], acc2[c]);
  }
  __shared__ float red[4][64][17];
  #pragma unroll
  for (int c = 0; c < 8; ++c) { red[wu][lane][2*c] = acc2[c].x; red[wu][lane][2*c+1] = acc2[c].y; }
  red[wu][lane][16] = den;
  __syncthreads();
  if (wu == 0) {
    size_t o = ((size_t)n*4 + h)*KC2 + kcg;
    pd[o] = red[0][lane][16] + red[1][lane][16] + red[2][lane][16] + red[3][lane][16];
    #pragma unroll
    for (int c = 0; c < 16; ++c)
      pacc[o*16 + c] = red[0][lane][c] + red[1][lane][c] + red[2][lane][c] + red[3][lane][c];
  }
}

__global__ void k_attn_combine(const float* __restrict__ pd, const float* __restrict__ pacc,
                               float* __restrict__ attn) {
  int t = blockIdx.x*256 + threadIdx.x;   // (n, h)
  if (t >= NN*4) return;
  float den = 0.f;
  #pragma unroll
  for (int kc = 0; kc < KC2; ++kc) den += pd[(size_t)t*KC2 + kc];
  float inv = 1.f/den;
  int n = t >> 2, h = t & 3;
  #pragma unroll
  for (int c = 0; c < 16; ++c) {
    float s = 0.f;
    #pragma unroll
    for (int kc = 0; kc < KC2; ++kc) s += pacc[((size_t)t*KC2 + kc)*16 + c];
    attn[(size_t)n*64 + h*16 + c] = s*inv;
  }
}

// ---------------- node-mean + folded output projection -> reps ----------------
__global__ void k_reps(const float* __restrict__ attn, const float* __restrict__ out_w,
                       const float* __restrict__ out_b, float* __restrict__ reps,
                       float* __restrict__ dout) {
  int m = blockIdx.x;
  __shared__ float part[4][64];
  __shared__ float abar[64];
  int c = threadIdx.x & 63, pp = threadIdx.x >> 6;
  float s = 0.f;
  const float* base = attn + (size_t)m*NMOD*64;
  for (int i = pp*256; i < pp*256 + 256; ++i) s += base[(size_t)i*64 + c];
  part[pp][c] = s;
  __syncthreads();
  if (pp == 0) abar[c] = (part[0][c]+part[1][c]+part[2][c]+part[3][c]) * (1.f/NMOD);
  __syncthreads();
  if (threadIdx.x < 64) {
    int j = threadIdx.x;
    float r = out_b[m*64 + j];
    const float* wr = out_w + (size_t)m*64*64 + (size_t)j*64;
    #pragma unroll
    for (int k = 0; k < 64; ++k) r += abar[k]*wr[k];
    reps[m*64 + j] = r;
    dout[2 + m*64 + j] = r;     // Output 1
  }
}

// ---------------- cross-attention + fusion + classifier (single block, lane-parallel) ----------------
__global__ __launch_bounds__(256) void k_final(const float* __restrict__ reps,
    const float* __restrict__ ca_in_w, const float* __restrict__ ca_in_b,
    const float* __restrict__ ca_out_w, const float* __restrict__ ca_out_b,
    const float* __restrict__ fusion_w, const float* __restrict__ fc_w,
    const float* __restrict__ fc_b, const float* __restrict__ c1_w,
    const float* __restrict__ c1_b, const float* __restrict__ c2_w,
    const float* __restrict__ c2_b, float* __restrict__ dout) {
  __shared__ float R[7][64];
  __shared__ float QKV[7][192];
  __shared__ float SC[4][7][8];
  __shared__ float AL[4][7][8];
  __shared__ float O[7][64];
  __shared__ float CR[7][64];
  __shared__ float W[8];
  __shared__ float part[4][64];
  __shared__ float FU[64];
  __shared__ float HM[32];
  int tid = threadIdx.x, lane = tid & 63;
  for (int i = tid; i < 448; i += 256) R[i>>6][i&63] = reps[i];
  __syncthreads();
  // Phase A: QKV = R @ ca_in_w^T + b. 1344 outputs, 4 threads per 64-dot.
  {
    int sub = tid & 3, tt0 = tid >> 2;
    #pragma unroll 3
    for (int it = 0; it < 21; ++it) {
      int t = tt0 + it*64;
      int r = t/192, j = t - r*192;
      const float4* wr = (const float4*)&ca_in_w[j*64 + sub*16];
      const float4* rr = (const float4*)&R[r][sub*16];
      float s = 0.f;
      #pragma unroll
      for (int c = 0; c < 4; ++c) {
        float4 a = rr[c], w4 = wr[c];
        s += a.x*w4.x + a.y*w4.y + a.z*w4.z + a.w*w4.w;
      }
      s += __shfl_xor(s, 1); s += __shfl_xor(s, 2);
      if (sub == 0) QKV[r][j] = s + ca_in_b[j];
    }
    if (tid == 252) {
      float p[7]; float den = 0.f;
      #pragma unroll
      for (int i = 0; i < 7; ++i) { p[i] = __expf(fusion_w[i]); den += p[i]; }
      float inv = 1.f/den;
      #pragma unroll
      for (int i = 0; i < 7; ++i) W[i] = p[i]*inv;
    }
  }
  __syncthreads();
  // Phase B: 196 (h,q,k) score exps
  if (tid < 196) {
    int hh = tid/49, rem = tid - hh*49, qi = rem/7, ki = rem - qi*7;
    float s = 0.f;
    #pragma unroll
    for (int c = 0; c < 16; ++c) s += QKV[qi][hh*16 + c]*QKV[ki][64 + hh*16 + c];
    SC[hh][qi][ki] = __expf(s*0.25f);
  }
  __syncthreads();
  if (tid < 28) {
    int hh = tid/7, qi = tid - hh*7;
    float den = 0.f;
    #pragma unroll
    for (int k = 0; k < 7; ++k) den += SC[hh][qi][k];
    float inv = 1.f/den;
    #pragma unroll
    for (int k = 0; k < 7; ++k) AL[hh][qi][k] = SC[hh][qi][k]*inv;
  }
  __syncthreads();
  // Phase C: O = alpha @ V
  for (int i = tid; i < 448; i += 256) {
    int qi = i >> 6, j = i & 63, hh = j >> 4;
    float s = 0.f;
    #pragma unroll
    for (int k = 0; k < 7; ++k) s += AL[hh][qi][k]*QKV[k][128 + j];
    O[qi][j] = s;
  }
  __syncthreads();
  // Phase D: CR = O @ ca_out_w^T + b
  {
    int sub = tid & 3, tt0 = tid >> 2;
    #pragma unroll
    for (int it = 0; it < 7; ++it) {
      int t = tt0 + it*64;
      int qi = t >> 6, j = t & 63;
      const float4* wr = (const float4*)&ca_out_w[j*64 + sub*16];
      const float4* orow = (const float4*)&O[qi][sub*16];
      float s = 0.f;
      #pragma unroll
      for (int c = 0; c < 4; ++c) {
        float4 a = orow[c], w4 = wr[c];
        s += a.x*w4.x + a.y*w4.y + a.z*w4.z + a.w*w4.w;
      }
      s += __shfl_xor(s, 1); s += __shfl_xor(s, 2);
      if (sub == 0) CR[qi][j] = s + ca_out_b[j];
    }
  }
  __syncthreads();
  // Phase F: FU[j] = fc_b[j] + sum_i CR[i]*W[i/64]*fc_w[i][j], split over 4 waves
  {
    int w = tid >> 6;
    float s = 0.f;
    #pragma unroll 4
    for (int i = w*112; i < w*112 + 112; ++i)
      s += CR[i>>6][i&63]*W[i>>6]*fc_w[(size_t)i*64 + lane];
    part[w][lane] = s;
  }
  __syncthreads();
  if (tid < 64) FU[tid] = part[0][tid] + part[1][tid] + part[2][tid] + part[3][tid] + fc_b[tid];
  __syncthreads();
  // Phase G: HM = relu(FU @ c1_w + b)
  if (tid < 128) {
    int sub = tid & 3, j = tid >> 2;
    float s = 0.f;
    #pragma unroll
    for (int c = 0; c < 16; ++c) { int k = sub*16 + c; s += FU[k]*c1_w[k*32 + j]; }
    s += __shfl_xor(s, 1); s += __shfl_xor(s, 2);
    if (sub == 0) HM[j] = fmaxf(s + c1_b[j], 0.f);
  }
  __syncthreads();
  if (tid < 2) {
    float s = c2_b[tid];
    #pragma unroll
    for (int k = 0; k < 32; ++k) s += HM[k]*c2_w[k*2 + tid];
    dout[tid] = s;              // Output 0
  }
}

extern "C" void kernel_launch(void* const* d_in, const int* in_sizes, int n_in,
                              void* d_out, int out_size, void* d_ws, size_t ws_size,
                              hipStream_t stream) {
  (void)in_sizes; (void)n_in; (void)out_size; (void)ws_size;
  const float* x       = (const float*)d_in[0];
  const int*   ei      = (const int*)d_in[1];
  const float* g1_w    = (const float*)d_in[3];
  const float* g1_as   = (const float*)d_in[4];
  const float* g1_ad   = (const float*)d_in[5];
  const float* g1_b    = (const float*)d_in[6];
  const float* g2_w    = (const float*)d_in[7];
  const float* g2_as   = (const float*)d_in[8];
  const float* g2_ad   = (const float*)d_in[9];
  const float* g2_b    = (const float*)d_in[10];
  const float* sa_in_w = (const float*)d_in[11];
  const float* sa_in_b = (const float*)d_in[12];
  const float* sa_out_w= (const float*)d_in[13];
  const float* sa_out_b= (const float*)d_in[14];
  const float* ca_in_w = (const float*)d_in[15];
  const float* ca_in_b = (const float*)d_in[16];
  const float* ca_out_w= (const float*)d_in[17];
  const float* ca_out_b= (const float*)d_in[18];
  const float* fusion_w= (const float*)d_in[19];
  const float* fc_w    = (const float*)d_in[20];
  const float* fc_b    = (const float*)d_in[21];
  const float* c1_w    = (const float*)d_in[22];
  const float* c1_b    = (const float*)d_in[23];
  const float* c2_w    = (const float*)d_in[24];
  const float* c2_b    = (const float*)d_in[25];
  float* dout = (float*)d_out;

  const int* src = ei;        // edge_index[0]
  const int* dst = ei + EE;   // edge_index[1]

  // ---- workspace carve (aliasing by lifetime) ----
  char* p = (char*)d_ws;
  int* cnt     = (int*)p; p += (size_t)NN*sizeof(int);
  int* rs      = (int*)p; p += (size_t)(NN+4)*sizeof(int);
  int* rs2     = (int*)p; p += (size_t)(NN+4)*sizeof(int);
  int* csr_src = (int*)p; p += (size_t)EE*sizeof(int);
  p = (char*)(((uintptr_t)p + 255) & ~(uintptr_t)255);
  float* h1f  = (float*)p; p += (size_t)NN*256*4;   // bf16 h1; later h2 partials; later qkv (f32)
  float* es1  = (float*)p; p += (size_t)NN*4*4;
  float* ed1  = (float*)p; p += (size_t)NN*4*4;
  float* gat1 = (float*)p; p += (size_t)NN*256*4;   // later: pacc
  float* h2f  = (float*)p; p += (size_t)NN*64*4;    // bf16 h2; later pd
  float* es2  = (float*)p; p += (size_t)NN*4;
  float* ed2  = (float*)p; p += (size_t)NN*4;
  float* z    = (float*)p; p += (size_t)NN*64*4;
  float* attn = (float*)p; p += (size_t)NN*64*4;
  float* reps = (float*)p; p += (size_t)MODS*64*4;
  bf16* h1    = (bf16*)h1f;
  bf16* h2    = (bf16*)h2f;
  float* h2a  = h1f;                 // K-split partials; h1 dead after k_agg4
  float* h2b  = h1f + (size_t)NN*64;
  float* qkv  = h1f;                 // h2a/h2b dead after k_scores1c
  float* pacc = gat1;                // NN*256 floats; gat1 dead after layer-2 gemm
  float* pd   = h2f;                 // NN*16 floats; h2 dead after k_agg1

  k_zero<<<NN/4/256, 256, 0, stream>>>(cnt);
  k_count<<<(EE+255)/256, 256, 0, stream>>>(dst, cnt);
  k_scan<<<1, 1024, 0, stream>>>(cnt, rs, rs2);
  k_fill<<<(EE+255)/256, 256, 0, stream>>>(src, dst, rs2, csr_src);

  // GAT layer 1 (h1 in bf16, scores fused into GEMM epilogue)
  k_gemm<128,256,false,64,1,true,true><<<MODS*16*4, 256, 0, stream>>>(
      x, g1_w, nullptr, h1, g1_as, g1_ad, es1, ed1);
  k_agg4<<<NN/4, 256, 0, stream>>>(h1, es1, ed1, rs, csr_src, g1_b, gat1);

  // GAT layer 2 (K-split 2; combine + scores fused; h2 in bf16)
  k_gemm<256,64,false,32,2,false,false><<<MODS*32*2, 256, 0, stream>>>(
      gat1, g2_w, nullptr, h2a, nullptr, nullptr, nullptr, nullptr);
  k_scores1c<<<NN/4, 256, 0, stream>>>(h2a, h2b, g2_as, g2_ad, h2, es2, ed2);
  k_agg1<<<NN/4, 256, 0, stream>>>(h2, es2, ed2, rs, csr_src, g2_b, z);

  // self-attention
  k_gemm<64,192,true,64,1,false,false><<<MODS*16*3, 256, 0, stream>>>(
      z, sa_in_w, sa_in_b, qkv, nullptr, nullptr, nullptr, nullptr);
  k_attn<<<MODS*16*4*KC2, 256, 0, stream>>>(qkv, pd, pacc);
  k_attn_combine<<<(NN*4+255)/256, 256, 0, stream>>>(pd, pacc, attn);

  // reps (Output 1), then head (Output 0)
  k_reps<<<MODS, 256, 0, stream>>>(attn, sa_out_w, sa_out_b, reps, dout);
  k_final<<<1, 256, 0, stream>>>(reps, ca_in_w, ca_in_b, ca_out_w, ca_out_b,
                                 fusion_w, fc_w, fc_b, c1_w, c1_b, c2_w, c2_b, dout);
}

// Round 6
// 145.969 us; speedup vs baseline: 2.4011x; 1.1754x over previous
//
#include <hip/hip_runtime.h>
#include <hip/hip_bf16.h>
#include <stdint.h>

#define MODS 7
#define NMOD 1024
#define EMOD 32768
#define NN (MODS*NMOD)   // 7168 nodes
#define EE (MODS*EMOD)   // 229376 edges
#define KC2 4            // block-level key chunks for self-attention
#define G1B (MODS*16*4)  // gemm1 blocks in fused launch

typedef __hip_bfloat16 bf16;

static __device__ __forceinline__ float lrelu(float x){ return x > 0.f ? x : 0.2f*x; }
static __device__ __forceinline__ float bfu(unsigned short u){ return __uint_as_float(((unsigned)u) << 16); }
static __device__ __forceinline__ float2 f2fma(float2 a, float2 b, float2 c){
  return make_float2(fmaf(a.x,b.x,c.x), fmaf(a.y,b.y,c.y));
}

// ---------------- per-module SGEMM body; optional bf16 out; fused GAT scores ----------------
// SC=4: JT==256, ct==head, es/ed per (node,head). SC=1: JT==64, single head.
template<int K, int JT, bool TB, int RT, bool OBF, int SC>
__device__ __forceinline__ void gemm_body(int b, const float* __restrict__ A,
    const float* __restrict__ B, const float* __restrict__ bias, void* __restrict__ Cv,
    const float* __restrict__ a_s, const float* __restrict__ a_d,
    float* __restrict__ es, float* __restrict__ ed) {
  constexpr int jt = JT/64;
  constexpr int rtiles = NMOD/RT;
  constexpr int RPT = RT/16;
  int ct = b % jt; b /= jt;
  int rt = b % rtiles; b /= rtiles;
  int m = b;
  int row0 = m*NMOD + rt*RT;
  int col0 = ct*64;
  __shared__ float Ast[32][RT+4];  // transposed: [kk][row]
  __shared__ float Bs[32][68];
  float acc[RPT][4] = {};
  int tid = threadIdx.x;
  int tr = (tid >> 4) * RPT;
  int tc = (tid & 15) * 4;
  const float* Bm = B + (size_t)m*K*JT;
  for (int k0 = 0; k0 < K; k0 += 32) {
    if constexpr (RT >= 32) {
      constexpr int ANUM = RT*32/1024;
      #pragma unroll
      for (int i = 0; i < ANUM; ++i) {
        int it = tid + i*256;
        int rr = it >> 3, kk0 = (it & 7)*4;
        float4 t = *(const float4*)&A[(size_t)(row0+rr)*K + k0 + kk0];
        Ast[kk0+0][rr] = t.x; Ast[kk0+1][rr] = t.y; Ast[kk0+2][rr] = t.z; Ast[kk0+3][rr] = t.w;
      }
    } else { // RT == 16: 128 float4s
      if (tid < 128) {
        int rr = tid >> 3, kk0 = (tid & 7)*4;
        float4 t = *(const float4*)&A[(size_t)(row0+rr)*K + k0 + kk0];
        Ast[kk0+0][rr] = t.x; Ast[kk0+1][rr] = t.y; Ast[kk0+2][rr] = t.z; Ast[kk0+3][rr] = t.w;
      }
    }
    #pragma unroll
    for (int i = 0; i < 2; ++i) {
      int it = tid + i*256;
      if (!TB) {
        int kk = it >> 4, jj0 = (it & 15)*4;
        float4 t = *(const float4*)&Bm[(size_t)(k0+kk)*JT + col0 + jj0];
        Bs[kk][jj0] = t.x; Bs[kk][jj0+1] = t.y; Bs[kk][jj0+2] = t.z; Bs[kk][jj0+3] = t.w;
      } else {
        int jj = it >> 3, kk0 = (it & 7)*4;
        float4 t = *(const float4*)&Bm[(size_t)(col0+jj)*K + k0 + kk0];
        Bs[kk0+0][jj] = t.x; Bs[kk0+1][jj] = t.y; Bs[kk0+2][jj] = t.z; Bs[kk0+3][jj] = t.w;
      }
    }
    __syncthreads();
    #pragma unroll
    for (int kk = 0; kk < 32; ++kk) {
      float4 bv = *(const float4*)&Bs[kk][tc];
      float av[RPT];
      if constexpr (RPT == 4) {
        float4 t = *(const float4*)&Ast[kk][tr];
        av[0] = t.x; av[1] = t.y; av[2] = t.z; av[3] = t.w;
      } else if constexpr (RPT == 2) {
        av[0] = Ast[kk][tr]; av[1] = Ast[kk][tr+1];
      } else {
        av[0] = Ast[kk][tr];
      }
      #pragma unroll
      for (int i = 0; i < RPT; ++i) {
        acc[i][0] += av[i]*bv.x; acc[i][1] += av[i]*bv.y;
        acc[i][2] += av[i]*bv.z; acc[i][3] += av[i]*bv.w;
      }
    }
    __syncthreads();
  }
  float4 bb = {0,0,0,0};
  if (bias) bb = *(const float4*)&bias[m*JT + col0 + tc];
  #pragma unroll
  for (int i = 0; i < RPT; ++i) {
    float4 o = { acc[i][0]+bb.x, acc[i][1]+bb.y, acc[i][2]+bb.z, acc[i][3]+bb.w };
    size_t idx = (size_t)(row0+tr+i)*JT + col0 + tc;
    if constexpr (OBF) {
      bf16* Cp = (bf16*)Cv;
      bf16 tmp[4] = { __float2bfloat16(o.x), __float2bfloat16(o.y),
                      __float2bfloat16(o.z), __float2bfloat16(o.w) };
      *(uint2*)&Cp[idx] = *(const uint2*)tmp;
    } else {
      float* Cp = (float*)Cv;
      *(float4*)&Cp[idx] = o;
    }
  }
  if constexpr (SC == 4) {
    int hh = ct;
    float4 as4 = *(const float4*)&a_s[(m*4 + hh)*64 + tc];
    float4 ad4 = *(const float4*)&a_d[(m*4 + hh)*64 + tc];
    #pragma unroll
    for (int i = 0; i < RPT; ++i) {
      float s = acc[i][0]*as4.x + acc[i][1]*as4.y + acc[i][2]*as4.z + acc[i][3]*as4.w;
      float d = acc[i][0]*ad4.x + acc[i][1]*ad4.y + acc[i][2]*ad4.z + acc[i][3]*ad4.w;
      #pragma unroll
      for (int off = 1; off < 16; off <<= 1) { s += __shfl_xor(s, off); d += __shfl_xor(d, off); }
      if ((tid & 15) == 0) {
        es[(row0+tr+i)*4 + hh] = s;
        ed[(row0+tr+i)*4 + hh] = d;
      }
    }
  }
  if constexpr (SC == 1) {
    float4 as4 = *(const float4*)&a_s[m*64 + tc];
    float4 ad4 = *(const float4*)&a_d[m*64 + tc];
    float s = acc[0][0]*as4.x + acc[0][1]*as4.y + acc[0][2]*as4.z + acc[0][3]*as4.w;
    float d = acc[0][0]*ad4.x + acc[0][1]*ad4.y + acc[0][2]*ad4.z + acc[0][3]*ad4.w;
    #pragma unroll
    for (int off = 1; off < 16; off <<= 1) { s += __shfl_xor(s, off); d += __shfl_xor(d, off); }
    if ((tid & 15) == 0) { es[row0+tr] = s; ed[row0+tr] = d; }
  }
}

// ---------------- per-module CSR count+scan in LDS (one block per module) ----------------
__device__ __forceinline__ void hist_body(int mm, const int* __restrict__ dst,
                                          int* __restrict__ rs, int* __restrict__ rs2) {
  __shared__ int hc[NMOD];
  __shared__ int hws[4];
  int tid = threadIdx.x;
  hc[tid] = 0; hc[tid+256] = 0; hc[tid+512] = 0; hc[tid+768] = 0;
  __syncthreads();
  const int4* d4 = (const int4*)(dst + mm*EMOD);
  int base = mm*NMOD;
  for (int it = tid; it < EMOD/4; it += 256) {
    int4 d = d4[it];
    atomicAdd(&hc[d.x - base], 1); atomicAdd(&hc[d.y - base], 1);
    atomicAdd(&hc[d.z - base], 1); atomicAdd(&hc[d.w - base], 1);
  }
  __syncthreads();
  int lane = tid & 63, wid = tid >> 6;
  int i0 = tid*4;
  int v0 = hc[i0], v1 = hc[i0+1], v2 = hc[i0+2], v3 = hc[i0+3];
  int T = v0+v1+v2+v3;
  int X = T;
  #pragma unroll
  for (int off = 1; off < 64; off <<= 1) { int t = __shfl_up(X, off); if (lane >= off) X += t; }
  if (lane == 63) hws[wid] = X;
  __syncthreads();
  int woff = 0;
  #pragma unroll
  for (int w = 0; w < 4; ++w) if (w < wid) woff += hws[w];
  int ex = mm*EMOD + woff + X - T;
  int4 o = make_int4(ex, ex+v0, ex+v0+v1, ex+v0+v1+v2);
  *(int4*)&rs[base + i0]  = o;
  *(int4*)&rs2[base + i0] = o;
  if (mm == MODS-1 && tid == 255) rs[NN] = EE;
}

// ---------------- fused launch: GEMM1(+scores) blocks [0,G1B) || CSR hist blocks [G1B,G1B+7) ----------------
__global__ __launch_bounds__(256) void k_g1h(const float* __restrict__ x,
    const float* __restrict__ g1w, bf16* __restrict__ h1,
    const float* __restrict__ a_s, const float* __restrict__ a_d,
    float* __restrict__ es, float* __restrict__ ed,
    const int* __restrict__ dst, int* __restrict__ rs, int* __restrict__ rs2) {
  if (blockIdx.x < G1B)
    gemm_body<128,256,false,64,true,4>(blockIdx.x, x, g1w, nullptr, h1, a_s, a_d, es, ed);
  else
    hist_body(blockIdx.x - G1B, dst, rs, rs2);
}

// ---------------- GEMM2 + fused H=1 scores, bf16 h2 out ----------------
__global__ __launch_bounds__(256) void k_g2s(const float* __restrict__ A,
    const float* __restrict__ B, bf16* __restrict__ h2,
    const float* __restrict__ a_s, const float* __restrict__ a_d,
    float* __restrict__ es, float* __restrict__ ed) {
  gemm_body<256,64,false,16,true,1>(blockIdx.x, A, B, nullptr, h2, a_s, a_d, es, ed);
}

// ---------------- QKV GEMM ----------------
__global__ __launch_bounds__(256) void k_gqkv(const float* __restrict__ A,
    const float* __restrict__ B, const float* __restrict__ bias, float* __restrict__ C) {
  gemm_body<64,192,true,64,false,0>(blockIdx.x, A, B, bias, C, nullptr, nullptr, nullptr, nullptr);
}

// rs2 doubles as the fill cursor (rebuilt every call by hist_body)
__global__ void k_fill(const int* __restrict__ src, const int* __restrict__ dst,
                       int* __restrict__ rs2, int* __restrict__ csr_src) {
  int e = blockIdx.x*256 + threadIdx.x;
  if (e < EE) {
    int pos = atomicAdd(&rs2[dst[e]], 1);
    csr_src[pos] = src[e];
  }
}

// ---------------- GAT layer-1 aggregation: one wave per node, all 4 heads, 8-wide ----------------
__global__ __launch_bounds__(256) void k_agg4(const bf16* __restrict__ h,
    const float* __restrict__ es, const float* __restrict__ ed, const int* __restrict__ rs,
    const int* __restrict__ csr_src, const float* __restrict__ bias, float* __restrict__ out) {
  int wid = __builtin_amdgcn_readfirstlane(threadIdx.x >> 6);
  int n = blockIdx.x*4 + wid;
  int lane = threadIdx.x & 63;
  int hh = lane >> 4;
  int m = n >> 10;
  const unsigned short* hp = (const unsigned short*)h;
  float edv = ed[n*4 + hh];
  float p0 = __expf(lrelu(es[n*4 + hh] + edv));   // self-loop
  float den = p0;
  ushort4 v0 = *(const ushort4*)&hp[(size_t)n*256 + lane*4];
  float a0 = p0*bfu(v0.x), a1 = p0*bfu(v0.y), a2 = p0*bfu(v0.z), a3 = p0*bfu(v0.w);
  int beg = rs[n], end = rs[n+1];
  int i = beg;
  for (; i + 8 <= end; i += 8) {
    int ss[8]; ushort4 ww[8]; float qq[8];
    #pragma unroll
    for (int k = 0; k < 8; ++k) ss[k] = csr_src[i+k];
    #pragma unroll
    for (int k = 0; k < 8; ++k) ww[k] = *(const ushort4*)&hp[(size_t)ss[k]*256 + lane*4];
    #pragma unroll
    for (int k = 0; k < 8; ++k) qq[k] = __expf(lrelu(es[ss[k]*4 + hh] + edv));
    #pragma unroll
    for (int k = 0; k < 8; ++k) {
      den += qq[k];
      a0 += qq[k]*bfu(ww[k].x); a1 += qq[k]*bfu(ww[k].y);
      a2 += qq[k]*bfu(ww[k].z); a3 += qq[k]*bfu(ww[k].w);
    }
  }
  for (; i < end; ++i) {
    int s = csr_src[i];
    ushort4 w = *(const ushort4*)&hp[(size_t)s*256 + lane*4];
    float q = __expf(lrelu(es[s*4 + hh] + edv));
    den += q;
    a0 += q*bfu(w.x); a1 += q*bfu(w.y); a2 += q*bfu(w.z); a3 += q*bfu(w.w);
  }
  float inv = 1.f/den;
  float4 bb = *(const float4*)&bias[m*256 + lane*4];
  float4 o = { fmaxf(a0*inv + bb.x, 0.f), fmaxf(a1*inv + bb.y, 0.f),
               fmaxf(a2*inv + bb.z, 0.f), fmaxf(a3*inv + bb.w, 0.f) };
  *(float4*)&out[(size_t)n*256 + lane*4] = o;
}

// ---------------- GAT layer-2 aggregation (H=1, per-node wave, 8-wide) ----------------
__global__ __launch_bounds__(256) void k_agg1(const bf16* __restrict__ h,
    const float* __restrict__ es, const float* __restrict__ ed, const int* __restrict__ rs,
    const int* __restrict__ csr_src, const float* __restrict__ bias, float* __restrict__ out) {
  int wid = __builtin_amdgcn_readfirstlane(threadIdx.x >> 6);
  int n = blockIdx.x*4 + wid;
  int lane = threadIdx.x & 63;
  int m = n >> 10;
  float edv = ed[n];
  float p0 = __expf(lrelu(es[n] + edv));
  float den = p0;
  float acc = p0 * __bfloat162float(h[(size_t)n*64 + lane]);
  int beg = rs[n], end = rs[n+1];
  int i = beg;
  for (; i + 8 <= end; i += 8) {
    int ss[8]; float vv[8]; float qq[8];
    #pragma unroll
    for (int k = 0; k < 8; ++k) ss[k] = csr_src[i+k];
    #pragma unroll
    for (int k = 0; k < 8; ++k) vv[k] = __bfloat162float(h[(size_t)ss[k]*64 + lane]);
    #pragma unroll
    for (int k = 0; k < 8; ++k) qq[k] = __expf(lrelu(es[ss[k]] + edv));
    #pragma unroll
    for (int k = 0; k < 8; ++k) { den += qq[k]; acc += qq[k]*vv[k]; }
  }
  for (; i < end; ++i) {
    int s = csr_src[i];
    float q = __expf(lrelu(es[s] + edv));
    den += q;
    acc += q * __bfloat162float(h[(size_t)s*64 + lane]);
  }
  float v = acc/den + bias[m*64 + lane];
  out[(size_t)n*64 + lane] = fmaxf(v, 0.f);
}

// ---------------- self-attention: lane=query, wave-uniform K/V s_loads, rotating K prefetch ----------------
__global__ __launch_bounds__(256) void k_attn(const float* __restrict__ qkv,
    float* __restrict__ pd, float* __restrict__ pacc) {
  int b = blockIdx.x;
  int kcg = b & (KC2-1); b /= KC2;
  int h = b & 3; b >>= 2;
  int qt = b & 15; int m = b >> 4;
  int lane = threadIdx.x & 63;
  int wu = __builtin_amdgcn_readfirstlane(threadIdx.x >> 6);
  int n = m*NMOD + qt*64 + lane;
  float2 q2[8];
  const float* qrow = qkv + (size_t)n*192 + h*16;
  #pragma unroll
  for (int c = 0; c < 8; ++c) {
    float2 t = *(const float2*)(qrow + 2*c);
    q2[c] = make_float2(t.x*0.25f, t.y*0.25f);
  }
  const float* kb = qkv + (size_t)(m*NMOD + kcg*256 + wu*64)*192 + 64 + h*16;
  float den = 0.f;
  float2 acc2[8] = {};
  float2 kreg[8];
  #pragma unroll
  for (int c = 0; c < 8; ++c) kreg[c] = ((const float2*)kb)[c];
  for (int j = 0; j < 64; ++j) {
    // prefetch next key row (j=63 reads key+64: stays inside the NN*256-float buffer)
    const float2* nk = (const float2*)(kb + (size_t)(j+1)*192);
    float2 knx[8];
    #pragma unroll
    for (int c = 0; c < 8; ++c) knx[c] = nk[c];
    float2 d0 = {0,0}, d1 = {0,0};
    #pragma unroll
    for (int c = 0; c < 8; c += 2) { d0 = f2fma(q2[c], kreg[c], d0); d1 = f2fma(q2[c+1], kreg[c+1], d1); }
    float p = __expf((d0.x + d0.y) + (d1.x + d1.y));
    den += p;
    const float2* vr2 = (const float2*)(kb + (size_t)j*192 + 64);
    float2 pp = {p, p};
    #pragma unroll
    for (int c = 0; c < 8; ++c) acc2[c] = f2fma(pp, vr2[c], acc2[c]);
    #pragma unroll
    for (int c = 0; c < 8; ++c) kreg[c] = knx[c];
  }
  __shared__ float red[4][64][17];
  #pragma unroll
  for (int c = 0; c < 8; ++c) { red[wu][lane][2*c] = acc2[c].x; red[wu][lane][2*c+1] = acc2[c].y; }
  red[wu][lane][16] = den;
  __syncthreads();
  if (wu == 0) {
    size_t o = ((size_t)n*4 + h)*KC2 + kcg;
    pd[o] = red[0][lane][16] + red[1][lane][16] + red[2][lane][16] + red[3][lane][16];
    #pragma unroll
    for (int c = 0; c < 16; ++c)
      pacc[o*16 + c] = red[0][lane][c] + red[1][lane][c] + red[2][lane][c] + red[3][lane][c];
  }
}

__global__ void k_attn_combine(const float* __restrict__ pd, const float* __restrict__ pacc,
                               float* __restrict__ attn) {
  int t = blockIdx.x*256 + threadIdx.x;   // (n, h)
  if (t >= NN*4) return;
  float den = 0.f;
  #pragma unroll
  for (int kc = 0; kc < KC2; ++kc) den += pd[(size_t)t*KC2 + kc];
  float inv = 1.f/den;
  int n = t >> 2, h = t & 3;
  #pragma unroll
  for (int c = 0; c < 16; ++c) {
    float s = 0.f;
    #pragma unroll
    for (int kc = 0; kc < KC2; ++kc) s += pacc[((size_t)t*KC2 + kc)*16 + c];
    attn[(size_t)n*64 + h*16 + c] = s*inv;
  }
}

// ---------------- node-mean + folded output projection -> reps ----------------
__global__ void k_reps(const float* __restrict__ attn, const float* __restrict__ out_w,
                       const float* __restrict__ out_b, float* __restrict__ reps,
                       float* __restrict__ dout) {
  int m = blockIdx.x;
  __shared__ float part[4][64];
  __shared__ float abar[64];
  int c = threadIdx.x & 63, pp = threadIdx.x >> 6;
  float s = 0.f;
  const float* base = attn + (size_t)m*NMOD*64;
  for (int i = pp*256; i < pp*256 + 256; ++i) s += base[(size_t)i*64 + c];
  part[pp][c] = s;
  __syncthreads();
  if (pp == 0) abar[c] = (part[0][c]+part[1][c]+part[2][c]+part[3][c]) * (1.f/NMOD);
  __syncthreads();
  if (threadIdx.x < 64) {
    int j = threadIdx.x;
    float r = out_b[m*64 + j];
    const float* wr = out_w + (size_t)m*64*64 + (size_t)j*64;
    #pragma unroll
    for (int k = 0; k < 64; ++k) r += abar[k]*wr[k];
    reps[m*64 + j] = r;
    dout[2 + m*64 + j] = r;     // Output 1
  }
}

// ---------------- cross-attention + fusion + classifier (single block, lane-parallel) ----------------
__global__ __launch_bounds__(256) void k_final(const float* __restrict__ reps,
    const float* __restrict__ ca_in_w, const float* __restrict__ ca_in_b,
    const float* __restrict__ ca_out_w, const float* __restrict__ ca_out_b,
    const float* __restrict__ fusion_w, const float* __restrict__ fc_w,
    const float* __restrict__ fc_b, const float* __restrict__ c1_w,
    const float* __restrict__ c1_b, const float* __restrict__ c2_w,
    const float* __restrict__ c2_b, float* __restrict__ dout) {
  __shared__ float R[7][64];
  __shared__ float QKV[7][192];
  __shared__ float SC[4][7][8];
  __shared__ float AL[4][7][8];
  __shared__ float O[7][64];
  __shared__ float CR[7][64];
  __shared__ float W[8];
  __shared__ float part[4][64];
  __shared__ float FU[64];
  __shared__ float HM[32];
  int tid = threadIdx.x, lane = tid & 63;
  for (int i = tid; i < 448; i += 256) R[i>>6][i&63] = reps[i];
  __syncthreads();
  // Phase A: QKV = R @ ca_in_w^T + b. 1344 outputs, 4 threads per 64-dot.
  {
    int sub = tid & 3, tt0 = tid >> 2;
    #pragma unroll 3
    for (int it = 0; it < 21; ++it) {
      int t = tt0 + it*64;
      int r = t/192, j = t - r*192;
      const float4* wr = (const float4*)&ca_in_w[j*64 + sub*16];
      const float4* rr = (const float4*)&R[r][sub*16];
      float s = 0.f;
      #pragma unroll
      for (int c = 0; c < 4; ++c) {
        float4 a = rr[c], w4 = wr[c];
        s += a.x*w4.x + a.y*w4.y + a.z*w4.z + a.w*w4.w;
      }
      s += __shfl_xor(s, 1); s += __shfl_xor(s, 2);
      if (sub == 0) QKV[r][j] = s + ca_in_b[j];
    }
    if (tid == 252) {
      float p[7]; float den = 0.f;
      #pragma unroll
      for (int i = 0; i < 7; ++i) { p[i] = __expf(fusion_w[i]); den += p[i]; }
      float inv = 1.f/den;
      #pragma unroll
      for (int i = 0; i < 7; ++i) W[i] = p[i]*inv;
    }
  }
  __syncthreads();
  // Phase B: 196 (h,q,k) score exps
  if (tid < 196) {
    int hh = tid/49, rem = tid - hh*49, qi = rem/7, ki = rem - qi*7;
    float s = 0.f;
    #pragma unroll
    for (int c = 0; c < 16; ++c) s += QKV[qi][hh*16 + c]*QKV[ki][64 + hh*16 + c];
    SC[hh][qi][ki] = __expf(s*0.25f);
  }
  __syncthreads();
  if (tid < 28) {
    int hh = tid/7, qi = tid - hh*7;
    float den = 0.f;
    #pragma unroll
    for (int k = 0; k < 7; ++k) den += SC[hh][qi][k];
    float inv = 1.f/den;
    #pragma unroll
    for (int k = 0; k < 7; ++k) AL[hh][qi][k] = SC[hh][qi][k]*inv;
  }
  __syncthreads();
  // Phase C: O = alpha @ V
  for (int i = tid; i < 448; i += 256) {
    int qi = i >> 6, j = i & 63, hh = j >> 4;
    float s = 0.f;
    #pragma unroll
    for (int k = 0; k < 7; ++k) s += AL[hh][qi][k]*QKV[k][128 + j];
    O[qi][j] = s;
  }
  __syncthreads();
  // Phase D: CR = O @ ca_out_w^T + b
  {
    int sub = tid & 3, tt0 = tid >> 2;
    #pragma unroll
    for (int it = 0; it < 7; ++it) {
      int t = tt0 + it*64;
      int qi = t >> 6, j = t & 63;
      const float4* wr = (const float4*)&ca_out_w[j*64 + sub*16];
      const float4* orow = (const float4*)&O[qi][sub*16];
      float s = 0.f;
      #pragma unroll
      for (int c = 0; c < 4; ++c) {
        float4 a = orow[c], w4 = wr[c];
        s += a.x*w4.x + a.y*w4.y + a.z*w4.z + a.w*w4.w;
      }
      s += __shfl_xor(s, 1); s += __shfl_xor(s, 2);
      if (sub == 0) CR[qi][j] = s + ca_out_b[j];
    }
  }
  __syncthreads();
  // Phase F: FU[j] = fc_b[j] + sum_i CR[i]*W[i/64]*fc_w[i][j], split over 4 waves
  {
    int w = tid >> 6;
    float s = 0.f;
    #pragma unroll 4
    for (int i = w*112; i < w*112 + 112; ++i)
      s += CR[i>>6][i&63]*W[i>>6]*fc_w[(size_t)i*64 + lane];
    part[w][lane] = s;
  }
  __syncthreads();
  if (tid < 64) FU[tid] = part[0][tid] + part[1][tid] + part[2][tid] + part[3][tid] + fc_b[tid];
  __syncthreads();
  // Phase G: HM = relu(FU @ c1_w + b)
  if (tid < 128) {
    int sub = tid & 3, j = tid >> 2;
    float s = 0.f;
    #pragma unroll
    for (int c = 0; c < 16; ++c) { int k = sub*16 + c; s += FU[k]*c1_w[k*32 + j]; }
    s += __shfl_xor(s, 1); s += __shfl_xor(s, 2);
    if (sub == 0) HM[j] = fmaxf(s + c1_b[j], 0.f);
  }
  __syncthreads();
  if (tid < 2) {
    float s = c2_b[tid];
    #pragma unroll
    for (int k = 0; k < 32; ++k) s += HM[k]*c2_w[k*2 + tid];
    dout[tid] = s;              // Output 0
  }
}

extern "C" void kernel_launch(void* const* d_in, const int* in_sizes, int n_in,
                              void* d_out, int out_size, void* d_ws, size_t ws_size,
                              hipStream_t stream) {
  (void)in_sizes; (void)n_in; (void)out_size; (void)ws_size;
  const float* x       = (const float*)d_in[0];
  const int*   ei      = (const int*)d_in[1];
  const float* g1_w    = (const float*)d_in[3];
  const float* g1_as   = (const float*)d_in[4];
  const float* g1_ad   = (const float*)d_in[5];
  const float* g1_b    = (const float*)d_in[6];
  const float* g2_w    = (const float*)d_in[7];
  const float* g2_as   = (const float*)d_in[8];
  const float* g2_ad   = (const float*)d_in[9];
  const float* g2_b    = (const float*)d_in[10];
  const float* sa_in_w = (const float*)d_in[11];
  const float* sa_in_b = (const float*)d_in[12];
  const float* sa_out_w= (const float*)d_in[13];
  const float* sa_out_b= (const float*)d_in[14];
  const float* ca_in_w = (const float*)d_in[15];
  const float* ca_in_b = (const float*)d_in[16];
  const float* ca_out_w= (const float*)d_in[17];
  const float* ca_out_b= (const float*)d_in[18];
  const float* fusion_w= (const float*)d_in[19];
  const float* fc_w    = (const float*)d_in[20];
  const float* fc_b    = (const float*)d_in[21];
  const float* c1_w    = (const float*)d_in[22];
  const float* c1_b    = (const float*)d_in[23];
  const float* c2_w    = (const float*)d_in[24];
  const float* c2_b    = (const float*)d_in[25];
  float* dout = (float*)d_out;

  const int* src = ei;        // edge_index[0]
  const int* dst = ei + EE;   // edge_index[1]

  // ---- workspace carve (aliasing by lifetime) ----
  char* p = (char*)d_ws;
  int* rs      = (int*)p; p += (size_t)(NN+4)*sizeof(int);
  int* rs2     = (int*)p; p += (size_t)(NN+4)*sizeof(int);
  int* csr_src = (int*)p; p += (size_t)EE*sizeof(int);
  p = (char*)(((uintptr_t)p + 255) & ~(uintptr_t)255);
  float* h1f  = (float*)p; p += (size_t)NN*256*4;   // bf16 h1; later qkv (f32, NN*192)
  float* es1  = (float*)p; p += (size_t)NN*4*4;
  float* ed1  = (float*)p; p += (size_t)NN*4*4;
  float* gat1 = (float*)p; p += (size_t)NN*256*4;   // later: pacc
  float* h2f  = (float*)p; p += (size_t)NN*64*4;    // bf16 h2; later pd
  float* es2  = (float*)p; p += (size_t)NN*4;
  float* ed2  = (float*)p; p += (size_t)NN*4;
  float* z    = (float*)p; p += (size_t)NN*64*4;
  float* attn = (float*)p; p += (size_t)NN*64*4;
  float* reps = (float*)p; p += (size_t)MODS*64*4;
  bf16* h1    = (bf16*)h1f;
  bf16* h2    = (bf16*)h2f;
  float* qkv  = h1f;                 // h1 dead after k_agg4 (gemm2 reads gat1)
  float* pacc = gat1;                // NN*4*KC2*16 floats; gat1 dead after k_g2s
  float* pd   = h2f;                 // NN*4*KC2 floats; h2 dead after k_agg1

  // K1: GEMM1 (+fused layer-1 scores) || per-module CSR count+scan
  k_g1h<<<G1B + MODS, 256, 0, stream>>>(x, g1_w, h1, g1_as, g1_ad, es1, ed1, dst, rs, rs2);
  // K2: CSR fill (rs2 = cursors)
  k_fill<<<(EE+255)/256, 256, 0, stream>>>(src, dst, rs2, csr_src);
  // K3: GAT layer-1 aggregation
  k_agg4<<<NN/4, 256, 0, stream>>>(h1, es1, ed1, rs, csr_src, g1_b, gat1);
  // K4: GEMM2 + fused layer-2 scores (bf16 h2)
  k_g2s<<<MODS*64, 256, 0, stream>>>(gat1, g2_w, h2, g2_as, g2_ad, es2, ed2);
  // K5: GAT layer-2 aggregation
  k_agg1<<<NN/4, 256, 0, stream>>>(h2, es2, ed2, rs, csr_src, g2_b, z);
  // K6: QKV projection
  k_gqkv<<<MODS*16*3, 256, 0, stream>>>(z, sa_in_w, sa_in_b, qkv);
  // K7: self-attention partials
  k_attn<<<MODS*16*4*KC2, 256, 0, stream>>>(qkv, pd, pacc);
  // K8: combine
  k_attn_combine<<<(NN*4+255)/256, 256, 0, stream>>>(pd, pacc, attn);
  // K9: reps (Output 1)
  k_reps<<<MODS, 256, 0, stream>>>(attn, sa_out_w, sa_out_b, reps, dout);
  // K10: head (Output 0)
  k_final<<<1, 256, 0, stream>>>(reps, ca_in_w, ca_in_b, ca_out_w, ca_out_b,
                                 fusion_w, fc_w, fc_b, c1_w, c1_b, c2_w, c2_b, dout);
}